// Round 1
// baseline (5656.242 us; speedup 1.0000x reference)
//
#include <hip/hip_runtime.h>
#include <hip/hip_bf16.h>

// ---------------- problem constants ----------------
constexpr int Bc = 32, Sc = 512, Tc = 128, Dc = 512, Ac = 512, Hc = 8;
constexpr int HDc = 64, FFc = 2048, Lc = 6, MDc = 512, Vc = 500;
constexpr int NTOK = Bc * Tc;   // 4096
constexpr int NMEM = Bc * Sc;   // 16384

// ---------------- helpers ----------------
__device__ __forceinline__ float wave_sum(float v) {
#pragma unroll
  for (int o = 32; o > 0; o >>= 1) v += __shfl_down(v, o);
  return v;
}
__device__ __forceinline__ float wave_max(float v) {
#pragma unroll
  for (int o = 32; o > 0; o >>= 1) v = fmaxf(v, __shfl_down(v, o));
  return v;
}

// ---------------- embedding + sinusoidal PE ----------------
__global__ __launch_bounds__(256) void embed_pe_k(const int* __restrict__ ys,
                                                  const float* __restrict__ emb,
                                                  float* __restrict__ x) {
  int tok = blockIdx.x;            // b*Tc + t
  int t = tok & (Tc - 1);
  int id = ys[tok];
  int j = threadIdx.x;             // 0..255
  int d0 = 2 * j;
  const float cdiv = -9.210340371976184f / (float)Dc;  // -ln(10000)/D
  float div = expf((float)d0 * cdiv);
  float ang = (float)t * div;
  float pe0 = sinf(ang), pe1 = cosf(ang);
  const float sc = 22.627416997969522f;  // sqrt(512)
  long base = (long)tok * Dc + d0;
  long ebase = (long)id * Dc + d0;
  x[base]     = emb[ebase]     * sc + pe0;
  x[base + 1] = emb[ebase + 1] * sc + pe1;
}

// ---------------- layernorm (one block per row, 256 thr, 2 elems/thr) ----------------
__global__ __launch_bounds__(256) void layernorm_k(const float* __restrict__ x,
                                                   const float* __restrict__ g,
                                                   const float* __restrict__ bta,
                                                   float* __restrict__ out) {
  int row = blockIdx.x;
  int tid = threadIdx.x;
  const float* xr = x + (long)row * Dc;
  float2 xv = *(const float2*)(xr + tid * 2);
  __shared__ float red[4];
  float s = wave_sum(xv.x + xv.y);
  if ((tid & 63) == 0) red[tid >> 6] = s;
  __syncthreads();
  float mean = (red[0] + red[1] + red[2] + red[3]) * (1.0f / Dc);
  float dx0 = xv.x - mean, dx1 = xv.y - mean;
  __syncthreads();
  float s2 = wave_sum(dx0 * dx0 + dx1 * dx1);
  if ((tid & 63) == 0) red[tid >> 6] = s2;
  __syncthreads();
  float var = (red[0] + red[1] + red[2] + red[3]) * (1.0f / Dc);
  float rstd = rsqrtf(var + 1e-5f);
  float2 o;
  o.x = dx0 * rstd * g[2 * tid] + bta[2 * tid];
  o.y = dx1 * rstd * g[2 * tid + 1] + bta[2 * tid + 1];
  *(float2*)(out + (long)row * Dc + tid * 2) = o;
}

// ---------------- softmax (self-attn): row len T=128, causal + pad mask ----------------
__global__ __launch_bounds__(128) void softmax_sa_k(float* __restrict__ sc,
                                                    const int* __restrict__ lens) {
  int row = blockIdx.x;              // (b*H + h)*T + t
  int t = row & (Tc - 1);
  int b = row >> 10;                 // / (H*T)
  int tid = threadIdx.x;             // = s
  float* p = sc + (long)row * Tc;
  int len = lens[b];
  bool masked = (tid > t) || (tid >= len);
  float v = masked ? -INFINITY : p[tid] * 0.125f;
  __shared__ float red[2];
  float m = wave_max(v);
  if ((tid & 63) == 0) red[tid >> 6] = m;
  __syncthreads();
  float mx = fmaxf(red[0], red[1]);
  float e = masked ? 0.0f : expf(v - mx);
  __shared__ float red2[2];
  float su = wave_sum(e);
  if ((tid & 63) == 0) red2[tid >> 6] = su;
  __syncthreads();
  float inv = 1.0f / (red2[0] + red2[1]);
  p[tid] = e * inv;
}

// ---------------- softmax (cross-attn): row len S=512, pad mask only ----------------
__global__ __launch_bounds__(256) void softmax_ca_k(float* __restrict__ sc,
                                                    const int* __restrict__ lens) {
  int row = blockIdx.x;              // (b*H + h)*T + t
  int b = row >> 10;
  int tid = threadIdx.x;
  float* p = sc + (long)row * Sc;
  int len = lens[b];
  int s0 = tid * 2;
  float2 v2 = *(const float2*)(p + s0);
  bool m0 = (s0 >= len), m1 = (s0 + 1 >= len);
  float v0 = m0 ? -INFINITY : v2.x * 0.125f;
  float v1 = m1 ? -INFINITY : v2.y * 0.125f;
  __shared__ float red[4];
  float m = wave_max(fmaxf(v0, v1));
  if ((tid & 63) == 0) red[tid >> 6] = m;
  __syncthreads();
  float mx = fmaxf(fmaxf(red[0], red[1]), fmaxf(red[2], red[3]));
  float e0 = m0 ? 0.0f : expf(v0 - mx);
  float e1 = m1 ? 0.0f : expf(v1 - mx);
  __syncthreads();
  float su = wave_sum(e0 + e1);
  if ((tid & 63) == 0) red[tid >> 6] = su;
  __syncthreads();
  float inv = 1.0f / (red[0] + red[1] + red[2] + red[3]);
  float2 o; o.x = e0 * inv; o.y = e1 * inv;
  *(float2*)(p + s0) = o;
}

// ---------------- generic tiled fp32 GEMM ----------------
// C[bat] = act( A[bat] @ B[bat](^T) + bias + res )
// 64x64 tile, TK=16, 256 threads, 4x4 per thread.
constexpr int LDSS = 68;  // padded LDS stride (multiple of 4 for float4, breaks bank-conflict)

template <bool TB, bool BIAS, bool RES, bool SWISH, bool NCH>
__global__ __launch_bounds__(256) void gemm_k(
    const float* __restrict__ Ag, const float* __restrict__ Bg,
    const float* __restrict__ bias, const float* resp, float* Cg,
    int M, int N, int K, int lda, int ldb, int ldc, int nbi,
    long batAo, long batAi, long batBo, long batBi, long batCo, long batCi) {
  int bat = blockIdx.z;
  int bo = bat / nbi, bi = bat - bo * nbi;
  const float* Ap = Ag + bo * batAo + bi * batAi;
  const float* Bp = Bg + bo * batBo + bi * batBi;
  float* Cp = Cg + bo * batCo + bi * batCi;
  const float* Rp = RES ? (resp + bo * batCo + bi * batCi) : nullptr;
  int m0 = blockIdx.y * 64, n0 = blockIdx.x * 64;
  __shared__ float As[16][LDSS];
  __shared__ float Bs[16][LDSS];
  int tid = threadIdx.x;
  int tx = tid & 15, ty = tid >> 4;
  float c[4][4] = {};
  for (int kt = 0; kt < K; kt += 16) {
    {  // A tile 64x16 -> As[k][m]
      int k = tid & 15, m = tid >> 4;
      const float* ap = Ap + (long)(m0 + m) * lda + kt + k;
#pragma unroll
      for (int i = 0; i < 4; i++) As[k][m + i * 16] = ap[(long)i * 16 * lda];
    }
    if (TB) {  // B is (N x K) row-major, want Bs[k][n]
      int k = tid & 15, n = tid >> 4;
      const float* bp = Bp + (long)(n0 + n) * ldb + kt + k;
#pragma unroll
      for (int i = 0; i < 4; i++) Bs[k][n + i * 16] = bp[(long)i * 16 * ldb];
    } else {   // B is (K x N) row-major
      int n = tid & 63, k = tid >> 6;
      int nn = n0 + n;
#pragma unroll
      for (int i = 0; i < 4; i++) {
        float val = 0.0f;
        if (!NCH || nn < N) val = Bp[(long)(kt + k + i * 4) * ldb + nn];
        Bs[k + i * 4][n] = val;
      }
    }
    __syncthreads();
#pragma unroll
    for (int kk = 0; kk < 16; kk++) {
      float a[4], b[4];
#pragma unroll
      for (int i = 0; i < 4; i++) a[i] = As[kk][ty * 4 + i];
#pragma unroll
      for (int j = 0; j < 4; j++) b[j] = Bs[kk][tx * 4 + j];
#pragma unroll
      for (int i = 0; i < 4; i++)
#pragma unroll
        for (int j = 0; j < 4; j++) c[i][j] += a[i] * b[j];
    }
    __syncthreads();
  }
#pragma unroll
  for (int i = 0; i < 4; i++) {
    int row = m0 + ty * 4 + i;
#pragma unroll
    for (int j = 0; j < 4; j++) {
      int col = n0 + tx * 4 + j;
      if (NCH && col >= N) continue;
      float v = c[i][j];
      if constexpr (BIAS) v += bias[col];
      if constexpr (RES) v += Rp[(long)row * ldc + col];
      if constexpr (SWISH) v = v / (1.0f + expf(-v));
      Cp[(long)row * ldc + col] = v;
    }
  }
}

// ---------------- host launcher ----------------
extern "C" void kernel_launch(void* const* d_in, const int* in_sizes, int n_in,
                              void* d_out, int out_size, void* d_ws, size_t ws_size,
                              hipStream_t stream) {
  const float* memory   = (const float*)d_in[0];
  const int*   mem_lens = (const int*)d_in[1];
  const int*   ys       = (const int*)d_in[2];
  const int*   ys_lens  = (const int*)d_in[3];
  const float* emb      = (const float*)d_in[4];
  const float* w_out    = (const float*)d_in[5];
  const float* b_out    = (const float*)d_in[6];
  const float* pp[26];
  for (int i = 0; i < 26; i++) pp[i] = (const float*)d_in[7 + i];
  // 0:ln_sa_g 1:ln_sa_b 2:sa_wq 3:sa_bq 4:sa_wk 5:sa_bk 6:sa_wv 7:sa_bv 8:sa_wo 9:sa_bo
  // 10:ln_ca_g 11:ln_ca_b 12:ca_wq 13:ca_bq 14:ca_wk 15:ca_bk 16:ca_wv 17:ca_bv 18:ca_wo 19:ca_bo
  // 20:ln_ff_g 21:ln_ff_b 22:ff_w1 23:ff_b1 24:ff_w2 25:ff_b2

  float* ws  = (float*)d_ws;
  float* X   = ws;
  float* TNb = X   + (long)NTOK * Dc;
  float* Qb  = TNb + (long)NTOK * Dc;
  float* Kb  = Qb  + (long)NTOK * Ac;
  float* Vb  = Kb  + (long)NMEM * Ac;
  float* Ob  = Vb  + (long)NMEM * Ac;
  float* SC  = Ob  + (long)NTOK * Ac;   // B*H*T*S floats (also aliased as FF hidden)
  float* FFH = SC;

  float* OUT = (float*)d_out;

  embed_pe_k<<<NTOK, 256, 0, stream>>>(ys, emb, X);

  for (int l = 0; l < Lc; l++) {
    const float* lnsg = pp[0] + (long)l * Dc;
    const float* lnsb = pp[1] + (long)l * Dc;
    const float* wq   = pp[2] + (long)l * Dc * Ac;
    const float* bq   = pp[3] + (long)l * Ac;
    const float* wk   = pp[4] + (long)l * Dc * Ac;
    const float* bk   = pp[5] + (long)l * Ac;
    const float* wv   = pp[6] + (long)l * Dc * Ac;
    const float* bv   = pp[7] + (long)l * Ac;
    const float* wo   = pp[8] + (long)l * Ac * Dc;
    const float* bo   = pp[9] + (long)l * Dc;
    const float* lncg = pp[10] + (long)l * Dc;
    const float* lncb = pp[11] + (long)l * Dc;
    const float* cwq  = pp[12] + (long)l * Dc * Ac;
    const float* cbq  = pp[13] + (long)l * Ac;
    const float* cwk  = pp[14] + (long)l * MDc * Ac;
    const float* cbk  = pp[15] + (long)l * Ac;
    const float* cwv  = pp[16] + (long)l * MDc * Ac;
    const float* cbv  = pp[17] + (long)l * Ac;
    const float* cwo  = pp[18] + (long)l * Ac * Dc;
    const float* cbo  = pp[19] + (long)l * Dc;
    const float* lnfg = pp[20] + (long)l * Dc;
    const float* lnfb = pp[21] + (long)l * Dc;
    const float* w1   = pp[22] + (long)l * Dc * FFc;
    const float* b1   = pp[23] + (long)l * FFc;
    const float* w2   = pp[24] + (long)l * FFc * Dc;
    const float* b2   = pp[25] + (long)l * Dc;

    // ---- self-attention ----
    layernorm_k<<<NTOK, 256, 0, stream>>>(X, lnsg, lnsb, TNb);
    gemm_k<false, true, false, false, false><<<dim3(8, 64, 1), 256, 0, stream>>>(
        TNb, wq, bq, nullptr, Qb, NTOK, Ac, Dc, Dc, Ac, Ac, 1, 0, 0, 0, 0, 0, 0);
    gemm_k<false, true, false, false, false><<<dim3(8, 64, 1), 256, 0, stream>>>(
        TNb, wk, bk, nullptr, Kb, NTOK, Ac, Dc, Dc, Ac, Ac, 1, 0, 0, 0, 0, 0, 0);
    gemm_k<false, true, false, false, false><<<dim3(8, 64, 1), 256, 0, stream>>>(
        TNb, wv, bv, nullptr, Vb, NTOK, Ac, Dc, Dc, Ac, Ac, 1, 0, 0, 0, 0, 0, 0);
    // scores: per (b,h): Q(T x 64) @ K(T x 64)^T -> (T x T)
    gemm_k<true, false, false, false, false><<<dim3(2, 2, Bc * Hc), 256, 0, stream>>>(
        Qb, Kb, nullptr, nullptr, SC, Tc, Tc, HDc, Ac, Ac, Tc, Hc,
        (long)Tc * Ac, 64, (long)Tc * Ac, 64, (long)Hc * Tc * Tc, (long)Tc * Tc);
    softmax_sa_k<<<Bc * Hc * Tc, 128, 0, stream>>>(SC, ys_lens);
    // PV: per (b,h): P(T x T) @ V(T x 64) -> (T x 64)
    gemm_k<false, false, false, false, false><<<dim3(1, 2, Bc * Hc), 256, 0, stream>>>(
        SC, Vb, nullptr, nullptr, Ob, Tc, HDc, Tc, Tc, Ac, Ac, Hc,
        (long)Hc * Tc * Tc, (long)Tc * Tc, (long)Tc * Ac, 64, (long)Tc * Ac, 64);
    // out proj + residual
    gemm_k<false, true, true, false, false><<<dim3(8, 64, 1), 256, 0, stream>>>(
        Ob, wo, bo, X, X, NTOK, Dc, Ac, Ac, Dc, Dc, 1, 0, 0, 0, 0, 0, 0);

    // ---- cross-attention ----
    layernorm_k<<<NTOK, 256, 0, stream>>>(X, lncg, lncb, TNb);
    gemm_k<false, true, false, false, false><<<dim3(8, 64, 1), 256, 0, stream>>>(
        TNb, cwq, cbq, nullptr, Qb, NTOK, Ac, Dc, Dc, Ac, Ac, 1, 0, 0, 0, 0, 0, 0);
    gemm_k<false, true, false, false, false><<<dim3(8, 256, 1), 256, 0, stream>>>(
        memory, cwk, cbk, nullptr, Kb, NMEM, Ac, MDc, MDc, Ac, Ac, 1, 0, 0, 0, 0, 0, 0);
    gemm_k<false, true, false, false, false><<<dim3(8, 256, 1), 256, 0, stream>>>(
        memory, cwv, cbv, nullptr, Vb, NMEM, Ac, MDc, MDc, Ac, Ac, 1, 0, 0, 0, 0, 0, 0);
    // scores: per (b,h): Q(T x 64) @ K(S x 64)^T -> (T x S)
    gemm_k<true, false, false, false, false><<<dim3(8, 2, Bc * Hc), 256, 0, stream>>>(
        Qb, Kb, nullptr, nullptr, SC, Tc, Sc, HDc, Ac, Ac, Sc, Hc,
        (long)Tc * Ac, 64, (long)Sc * Ac, 64, (long)Hc * Tc * Sc, (long)Tc * Sc);
    softmax_ca_k<<<Bc * Hc * Tc, 256, 0, stream>>>(SC, mem_lens);
    // PV: per (b,h): P(T x S) @ V(S x 64) -> (T x 64)
    gemm_k<false, false, false, false, false><<<dim3(1, 2, Bc * Hc), 256, 0, stream>>>(
        SC, Vb, nullptr, nullptr, Ob, Tc, HDc, Sc, Sc, Ac, Ac, Hc,
        (long)Hc * Tc * Sc, (long)Tc * Sc, (long)Sc * Ac, 64, (long)Tc * Ac, 64);
    gemm_k<false, true, true, false, false><<<dim3(8, 64, 1), 256, 0, stream>>>(
        Ob, cwo, cbo, X, X, NTOK, Dc, Ac, Ac, Dc, Dc, 1, 0, 0, 0, 0, 0, 0);

    // ---- feed-forward ----
    layernorm_k<<<NTOK, 256, 0, stream>>>(X, lnfg, lnfb, TNb);
    gemm_k<false, true, false, true, false><<<dim3(32, 64, 1), 256, 0, stream>>>(
        TNb, w1, b1, nullptr, FFH, NTOK, FFc, Dc, Dc, FFc, FFc, 1, 0, 0, 0, 0, 0, 0);
    gemm_k<false, true, true, false, false><<<dim3(8, 64, 1), 256, 0, stream>>>(
        FFH, w2, b2, X, X, NTOK, Dc, FFc, FFc, Dc, Dc, 1, 0, 0, 0, 0, 0, 0);
  }

  // final projection (N=500, bounds-checked)
  gemm_k<false, true, false, false, true><<<dim3(8, 64, 1), 256, 0, stream>>>(
      X, w_out, b_out, nullptr, OUT, NTOK, Vc, Dc, Dc, Vc, Vc, 1, 0, 0, 0, 0, 0, 0);
}

// Round 2
// 1889.180 us; speedup vs baseline: 2.9940x; 2.9940x over previous
//
#include <hip/hip_runtime.h>
#include <hip/hip_bf16.h>
#include <hip/hip_fp16.h>

// ---------------- problem constants ----------------
constexpr int Bc = 32, Sc = 512, Tc = 128, Dc = 512, Ac = 512, Hc = 8;
constexpr int HDc = 64, FFc = 2048, Lc = 6, Vc = 500;
constexpr int NTOK = Bc * Tc;   // 4096
constexpr int NMEM = Bc * Sc;   // 16384

typedef unsigned short u16;
typedef __attribute__((ext_vector_type(8))) short short8;  // 8 bf16 (4 VGPRs)
typedef __attribute__((ext_vector_type(4))) float f32x4;   // MFMA accumulator

__device__ __forceinline__ u16 bfc(float x) {
  __hip_bfloat16 h = __float2bfloat16(x);
  return *reinterpret_cast<u16*>(&h);
}

// async global->LDS, 16B per lane. LDS dest = wave-uniform base + lane*16.
__device__ __forceinline__ void gload16(const void* g, void* l) {
  __builtin_amdgcn_global_load_lds(
      (const __attribute__((address_space(1))) unsigned int*)g,
      (__attribute__((address_space(3))) unsigned int*)l, 16, 0, 0);
}

__device__ __forceinline__ float wave_sum(float v) {
#pragma unroll
  for (int o = 32; o > 0; o >>= 1) v += __shfl_down(v, o);
  return v;
}
__device__ __forceinline__ float wave_max(float v) {
#pragma unroll
  for (int o = 32; o > 0; o >>= 1) v = fmaxf(v, __shfl_down(v, o));
  return v;
}

// ---------------- embedding + sinusoidal PE (fp32 residual stream) ----------------
__global__ __launch_bounds__(256) void embed_pe_k(const int* __restrict__ ys,
                                                  const float* __restrict__ emb,
                                                  float* __restrict__ x) {
  int tok = blockIdx.x;
  int t = tok & (Tc - 1);
  int id = ys[tok];
  int j = threadIdx.x;
  int d0 = 2 * j;
  const float cdiv = -9.210340371976184f / (float)Dc;
  float div = expf((float)d0 * cdiv);
  float ang = (float)t * div;
  float pe0 = sinf(ang), pe1 = cosf(ang);
  const float sc = 22.627416997969522f;  // sqrt(512)
  long base = (long)tok * Dc + d0;
  long ebase = (long)id * Dc + d0;
  x[base]     = emb[ebase]     * sc + pe0;
  x[base + 1] = emb[ebase + 1] * sc + pe1;
}

// ---------------- layernorm fp32 -> bf16 ----------------
__global__ __launch_bounds__(256) void layernorm_k(const float* __restrict__ x,
                                                   const float* __restrict__ g,
                                                   const float* __restrict__ bta,
                                                   u16* __restrict__ out) {
  int row = blockIdx.x;
  int tid = threadIdx.x;
  const float* xr = x + (long)row * Dc;
  float2 xv = *(const float2*)(xr + tid * 2);
  __shared__ float red[4];
  float s = wave_sum(xv.x + xv.y);
  if ((tid & 63) == 0) red[tid >> 6] = s;
  __syncthreads();
  float mean = (red[0] + red[1] + red[2] + red[3]) * (1.0f / Dc);
  float dx0 = xv.x - mean, dx1 = xv.y - mean;
  __syncthreads();
  float s2 = wave_sum(dx0 * dx0 + dx1 * dx1);
  if ((tid & 63) == 0) red[tid >> 6] = s2;
  __syncthreads();
  float var = (red[0] + red[1] + red[2] + red[3]) * (1.0f / Dc);
  float rstd = rsqrtf(var + 1e-5f);
  ushort2 o;
  o.x = bfc(dx0 * rstd * g[2 * tid] + bta[2 * tid]);
  o.y = bfc(dx1 * rstd * g[2 * tid + 1] + bta[2 * tid + 1]);
  *(ushort2*)(out + (long)row * Dc + tid * 2) = o;
}

// ---------------- softmax self-attn: fp16 scores in, bf16 P out (in place) ----------------
__global__ __launch_bounds__(128) void softmax_sa_k(u16* __restrict__ sc,
                                                    const int* __restrict__ lens) {
  int row = blockIdx.x;              // (b*H + h)*T + t
  int t = row & (Tc - 1);
  int b = row >> 10;
  int tid = threadIdx.x;
  const __half* p = (const __half*)sc + (long)row * Tc;
  u16* pw = sc + (long)row * Tc;
  int len = lens[b];
  bool masked = (tid > t) || (tid >= len);
  float v = masked ? -INFINITY : __half2float(p[tid]) * 0.125f;
  __shared__ float red[2];
  float m = wave_max(v);
  if ((tid & 63) == 0) red[tid >> 6] = m;
  __syncthreads();
  float mx = fmaxf(red[0], red[1]);
  float e = masked ? 0.0f : expf(v - mx);
  __shared__ float red2[2];
  float su = wave_sum(e);
  if ((tid & 63) == 0) red2[tid >> 6] = su;
  __syncthreads();
  float inv = 1.0f / (red2[0] + red2[1]);
  pw[tid] = bfc(e * inv);
}

// ---------------- softmax cross-attn: row len 512 ----------------
__global__ __launch_bounds__(256) void softmax_ca_k(u16* __restrict__ sc,
                                                    const int* __restrict__ lens) {
  int row = blockIdx.x;
  int b = row >> 10;
  int tid = threadIdx.x;
  const __half* p = (const __half*)sc + (long)row * Sc;
  u16* pw = sc + (long)row * Sc;
  int len = lens[b];
  int s0 = tid * 2;
  float v0f = __half2float(p[s0]), v1f = __half2float(p[s0 + 1]);
  bool m0 = (s0 >= len), m1 = (s0 + 1 >= len);
  float v0 = m0 ? -INFINITY : v0f * 0.125f;
  float v1 = m1 ? -INFINITY : v1f * 0.125f;
  __shared__ float red[4];
  float m = wave_max(fmaxf(v0, v1));
  if ((tid & 63) == 0) red[tid >> 6] = m;
  __syncthreads();
  float mx = fmaxf(fmaxf(red[0], red[1]), fmaxf(red[2], red[3]));
  float e0 = m0 ? 0.0f : expf(v0 - mx);
  float e1 = m1 ? 0.0f : expf(v1 - mx);
  __syncthreads();
  float su = wave_sum(e0 + e1);
  if ((tid & 63) == 0) red[tid >> 6] = su;
  __syncthreads();
  float inv = 1.0f / (red[0] + red[1] + red[2] + red[3]);
  pw[s0] = bfc(e0 * inv);
  pw[s0 + 1] = bfc(e1 * inv);
}

// ---------------- weight transpose+convert: W(K x N) fp32 -> Wt(Npad x K) bf16 ----------------
__global__ __launch_bounds__(256) void wtrans_k(const float* __restrict__ src,
                                                u16* __restrict__ dst,
                                                int K, int N, long srcStride, long dstStride) {
  int z = blockIdx.z;
  src += z * srcStride;
  dst += z * dstStride;
  __shared__ float t[32][33];
  int n0 = blockIdx.x * 32, k0 = blockIdx.y * 32;
  int tx = threadIdx.x & 31, ty = threadIdx.x >> 5;  // 32 x 8
#pragma unroll
  for (int i = 0; i < 4; i++) {
    int n = n0 + tx;
    t[ty + 8 * i][tx] = (n < N) ? src[(long)(k0 + ty + 8 * i) * N + n] : 0.0f;
  }
  __syncthreads();
#pragma unroll
  for (int i = 0; i < 4; i++) {
    dst[(long)(n0 + ty + 8 * i) * K + k0 + tx] = bfc(t[tx][ty + 8 * i]);
  }
}

// ---------------- V transpose (bf16): V[b*Scur+s][512] -> Vt[b*512+c][Scur] ----------------
__global__ __launch_bounds__(256) void vtrans_k(const u16* __restrict__ V,
                                                u16* __restrict__ Vt, int Scur) {
  int b = blockIdx.z;
  int c0 = blockIdx.x * 32, s0 = blockIdx.y * 32;
  __shared__ u16 t[32][33];
  int tx = threadIdx.x & 31, ty = threadIdx.x >> 5;
#pragma unroll
  for (int i = 0; i < 4; i++)
    t[ty + 8 * i][tx] = V[((long)b * Scur + s0 + ty + 8 * i) * 512 + c0 + tx];
  __syncthreads();
#pragma unroll
  for (int i = 0; i < 4; i++)
    Vt[((long)b * 512 + c0 + ty + 8 * i) * Scur + s0 + tx] = t[tx][ty + 8 * i];
}

// ---------------- fp32 -> bf16 convert ----------------
__global__ __launch_bounds__(256) void f2b_k(const float* __restrict__ in,
                                             u16* __restrict__ out, long n) {
  long i = ((long)blockIdx.x * 256 + threadIdx.x) * 4;
  if (i >= n) return;
  float4 v = *(const float4*)(in + i);
  ushort4 o;
  o.x = bfc(v.x); o.y = bfc(v.y); o.z = bfc(v.z); o.w = bfc(v.w);
  *(ushort4*)(out + i) = o;
}

// ---------------- bf16 MFMA GEMM (m97 structure) ----------------
// C = act(A(MxK,bf16) @ Bt(NxK,bf16)^T + bias [+ R]); BM=128, BN=32*WTN, BK=32.
// 256 threads = 4 waves in 2x2; per wave 4xWTN frags of 16x16 via mfma_f32_16x16x32_bf16.
// OMODE: 0 = bf16 out, 1 = fp32 out, 2 = fp16 out.
template <int WTN, int OMODE, bool BIAS, bool RES, bool SWISH>
__global__ __launch_bounds__(256) void mgemm_k(
    const u16* __restrict__ A, const u16* __restrict__ Bt,
    const float* __restrict__ bias0, const float* __restrict__ bias1,
    const float* __restrict__ bias2,
    void* __restrict__ Cv, const float* __restrict__ R,
    int N, int K, int lda, int ldb, int ldc, int nbi,
    long batAo, long batAi, long batBo, long batBi, long batCo, long batCi) {
  constexpr int BN = 32 * WTN;
  int z = blockIdx.z;
  int bo = z / nbi, bi = z - bo * nbi;
  const u16* Ab = A + bo * batAo + bi * batAi;
  const u16* Bb = Bt + bo * batBo + bi * batBi;
  long coff = bo * batCo + bi * batCi;
  const float* bias = nullptr;
  if constexpr (BIAS) bias = (bi == 0) ? bias0 : ((bi == 1) ? bias1 : bias2);
  int m0 = blockIdx.y * 128, n0 = blockIdx.x * BN;

  __shared__ __align__(16) u16 As[128 * 32];
  __shared__ __align__(16) u16 Bs[BN * 32];

  int tid = threadIdx.x;
  int lane = tid & 63, wid = tid >> 6;
  int wm = wid >> 1, wn = wid & 1;
  int fr = lane & 15, ks = lane >> 4;

  f32x4 acc[4][WTN];
#pragma unroll
  for (int i = 0; i < 4; i++)
#pragma unroll
    for (int j = 0; j < WTN; j++) acc[i][j] = (f32x4){0.f, 0.f, 0.f, 0.f};

  const u16* ga = Ab + (long)(m0 + (tid >> 2)) * lda + ((tid & 3) << 3);
  const u16* gb = Bb + (long)(n0 + (tid >> 2)) * ldb + ((tid & 3) << 3);
  u16* lA = &As[tid * 8];
  u16* lB = &Bs[tid * 8];

  for (int kt = 0; kt < K; kt += 32) {
    gload16(ga + kt, lA);
    gload16(ga + kt + (long)64 * lda, lA + 2048);
    if constexpr (WTN == 4) {
      gload16(gb + kt, lB);
      gload16(gb + kt + (long)64 * ldb, lB + 2048);
    } else {
      gload16(gb + kt, lB);  // 64 rows: all 256 threads cover 64x32 tile
    }
    __syncthreads();
    short8 av[4], bv[WTN];
#pragma unroll
    for (int i = 0; i < 4; i++)
      av[i] = *(const short8*)&As[(wm * 64 + i * 16 + fr) * 32 + ks * 8];
#pragma unroll
    for (int j = 0; j < WTN; j++)
      bv[j] = *(const short8*)&Bs[(wn * 16 * WTN + j * 16 + fr) * 32 + ks * 8];
#pragma unroll
    for (int i = 0; i < 4; i++)
#pragma unroll
      for (int j = 0; j < WTN; j++)
        acc[i][j] = __builtin_amdgcn_mfma_f32_16x16x32_bf16(av[i], bv[j], acc[i][j], 0, 0, 0);
    __syncthreads();
  }

  int rbase = m0 + wm * 64 + (lane >> 4) * 4;
  int cbase = n0 + wn * 16 * WTN + fr;
#pragma unroll
  for (int i = 0; i < 4; i++) {
#pragma unroll
    for (int j = 0; j < WTN; j++) {
      int col = cbase + j * 16;
      if (col >= N) continue;
      float bb = 0.0f;
      if constexpr (BIAS) bb = bias[col];
#pragma unroll
      for (int r = 0; r < 4; r++) {
        int row = rbase + i * 16 + r;
        float v = acc[i][j][r] + bb;
        long idx = coff + (long)row * ldc + col;
        if constexpr (RES) v += R[idx];
        if constexpr (SWISH) v = v / (1.0f + expf(-v));
        if constexpr (OMODE == 0) ((u16*)Cv)[idx] = bfc(v);
        else if constexpr (OMODE == 1) ((float*)Cv)[idx] = v;
        else ((__half*)Cv)[idx] = __float2half(v);
      }
    }
  }
}

// ---------------- host launcher ----------------
extern "C" void kernel_launch(void* const* d_in, const int* in_sizes, int n_in,
                              void* d_out, int out_size, void* d_ws, size_t ws_size,
                              hipStream_t stream) {
  const float* memory   = (const float*)d_in[0];
  const int*   mem_lens = (const int*)d_in[1];
  const int*   ys       = (const int*)d_in[2];
  const int*   ys_lens  = (const int*)d_in[3];
  const float* emb      = (const float*)d_in[4];
  const float* w_out    = (const float*)d_in[5];
  const float* b_out    = (const float*)d_in[6];
  const float* pp[26];
  for (int i = 0; i < 26; i++) pp[i] = (const float*)d_in[7 + i];

  // ---- ws layout (bytes; total ~152.5 MiB, fp32 baseline proved >=163.6 MiB) ----
  constexpr long PLW = 4194304;  // bf16 elems of transposed weights per layer
  constexpr long OFF_SAQ = 0, OFF_SAK = 262144, OFF_SAV = 524288, OFF_SAO = 786432,
                 OFF_CAQ = 1048576, OFF_CAK = 1310720, OFF_CAV = 1572864,
                 OFF_CAO = 1835008, OFF_FF1 = 2097152, OFF_FF2 = 3145728,
                 OFF_WOUT = 6 * PLW;  // + 512*512
  u16*   Wt   = (u16*)d_ws;                          // 25,427,968 u16
  float* X    = (float*)(Wt + 25427968);             // 2,097,152 f32
  u16*   TO   = (u16*)(X + 2097152);                 // 2,097,152 bf16 (LN out / attn out)
  u16*   QKV  = TO + 2097152;                        // 3 x 2,097,152 bf16
  u16*   memb = QKV + 3 * 2097152;                   // 8,388,608 bf16
  u16*   Kb   = memb + 8388608;                      // 8,388,608 bf16 (cross K)
  u16*   SCw  = Kb + 8388608;                        // 16,777,216 (half scores / bf16 P / Vtmp / FFH)
  u16*   Vt   = SCw + 16777216;                      // 8,388,608 bf16
  __half* SCh = (__half*)SCw;
  float* OUT  = (float*)d_out;

  // ---- weight transposes (per launch; deterministic) ----
  auto WT = [&](const float* src, long dstoff, int K, int N, int Npad, int Lz,
                long srcStride, long dstStride) {
    dim3 g(Npad / 32, K / 32, Lz);
    wtrans_k<<<g, 256, 0, stream>>>(src, Wt + dstoff, K, N, srcStride, dstStride);
  };
  WT(pp[2],  OFF_SAQ, 512, 512, 512, Lc, 262144, PLW);
  WT(pp[4],  OFF_SAK, 512, 512, 512, Lc, 262144, PLW);
  WT(pp[6],  OFF_SAV, 512, 512, 512, Lc, 262144, PLW);
  WT(pp[8],  OFF_SAO, 512, 512, 512, Lc, 262144, PLW);
  WT(pp[12], OFF_CAQ, 512, 512, 512, Lc, 262144, PLW);
  WT(pp[14], OFF_CAK, 512, 512, 512, Lc, 262144, PLW);
  WT(pp[16], OFF_CAV, 512, 512, 512, Lc, 262144, PLW);
  WT(pp[18], OFF_CAO, 512, 512, 512, Lc, 262144, PLW);
  WT(pp[22], OFF_FF1, 512, 2048, 2048, Lc, 1048576, PLW);
  WT(pp[24], OFF_FF2, 2048, 512, 512, Lc, 1048576, PLW);
  WT(w_out,  OFF_WOUT, 512, 500, 512, 1, 0, 0);

  f2b_k<<<(NMEM * Dc / 4 + 255) / 256, 256, 0, stream>>>(memory, memb, (long)NMEM * Dc);
  embed_pe_k<<<NTOK, 256, 0, stream>>>(ys, emb, X);

  for (int l = 0; l < Lc; l++) {
    const u16* WtL = Wt + (long)l * PLW;

    // ======== self-attention ========
    layernorm_k<<<NTOK, 256, 0, stream>>>(X, pp[0] + (long)l * Dc, pp[1] + (long)l * Dc, TO);
    // QKV batched (z=0,1,2)
    mgemm_k<4, 0, true, false, false><<<dim3(4, 32, 3), 256, 0, stream>>>(
        TO, WtL + OFF_SAQ, pp[3] + (long)l * Ac, pp[5] + (long)l * Ac, pp[7] + (long)l * Ac,
        QKV, nullptr, 512, 512, 512, 512, 512, 3, 0, 0, 0, 262144, 0, 2097152);
    // V self -> Vt [b][512][128]
    vtrans_k<<<dim3(16, 4, Bc), 256, 0, stream>>>(QKV + 2 * 2097152, Vt, Tc);
    // scores: per (b,h) Q(128x64) @ K(128x64)^T -> half
    mgemm_k<4, 2, false, false, false><<<dim3(1, 1, Bc * Hc), 256, 0, stream>>>(
        QKV, QKV + 2097152, nullptr, nullptr, nullptr, SCh, nullptr,
        128, 64, 512, 512, 128, Hc,
        (long)Tc * 512, 64, (long)Tc * 512, 64, (long)Hc * Tc * Tc, (long)Tc * Tc);
    softmax_sa_k<<<Bc * Hc * Tc, 128, 0, stream>>>(SCw, ys_lens);
    // PV: per (b,h) P(128x128) @ Vt(64x128)^T -> TO bf16
    mgemm_k<2, 0, false, false, false><<<dim3(1, 1, Bc * Hc), 256, 0, stream>>>(
        SCw, Vt, nullptr, nullptr, nullptr, TO, nullptr,
        64, 128, 128, 128, 512, Hc,
        (long)Hc * Tc * Tc, (long)Tc * Tc, (long)512 * Tc, (long)64 * Tc, (long)Tc * 512, 64);
    // out proj + residual into X (fp32)
    mgemm_k<4, 1, true, true, false><<<dim3(4, 32, 1), 256, 0, stream>>>(
        TO, WtL + OFF_SAO, pp[9] + (long)l * Dc, nullptr, nullptr, X, X,
        512, 512, 512, 512, 512, 1, 0, 0, 0, 0, 0, 0);

    // ======== cross-attention ========
    layernorm_k<<<NTOK, 256, 0, stream>>>(X, pp[10] + (long)l * Dc, pp[11] + (long)l * Dc, TO);
    mgemm_k<4, 0, true, false, false><<<dim3(4, 32, 1), 256, 0, stream>>>(
        TO, WtL + OFF_CAQ, pp[13] + (long)l * Ac, nullptr, nullptr, QKV, nullptr,
        512, 512, 512, 512, 512, 1, 0, 0, 0, 0, 0, 0);
    // K and V(tmp in SC region) batched (z=0: Kb, z=1: Vtmp = SCw) — contiguous stride
    mgemm_k<4, 0, true, false, false><<<dim3(4, 128, 2), 256, 0, stream>>>(
        memb, WtL + OFF_CAK, pp[15] + (long)l * Ac, pp[17] + (long)l * Ac, nullptr,
        Kb, nullptr, 512, 512, 512, 512, 512, 2, 0, 0, 0, 262144, 0, 8388608);
    // Vtmp -> Vt [b][512][512]
    vtrans_k<<<dim3(16, 16, Bc), 256, 0, stream>>>(SCw, Vt, Sc);
    // scores: per (b,h) Q(128x64) @ K(512x64)^T -> half (overwrites Vtmp)
    mgemm_k<4, 2, false, false, false><<<dim3(4, 1, Bc * Hc), 256, 0, stream>>>(
        QKV, Kb, nullptr, nullptr, nullptr, SCh, nullptr,
        512, 64, 512, 512, 512, Hc,
        (long)Tc * 512, 64, (long)Sc * 512, 64, (long)Hc * Tc * Sc, (long)Tc * Sc);
    softmax_ca_k<<<Bc * Hc * Tc, 256, 0, stream>>>(SCw, mem_lens);
    // PV: per (b,h) P(128x512) @ Vt(64x512)^T -> TO
    mgemm_k<2, 0, false, false, false><<<dim3(1, 1, Bc * Hc), 256, 0, stream>>>(
        SCw, Vt, nullptr, nullptr, nullptr, TO, nullptr,
        64, 512, 512, 512, 512, Hc,
        (long)Hc * Tc * Sc, (long)Tc * Sc, (long)512 * Sc, (long)64 * Sc, (long)Tc * 512, 64);
    mgemm_k<4, 1, true, true, false><<<dim3(4, 32, 1), 256, 0, stream>>>(
        TO, WtL + OFF_CAO, pp[19] + (long)l * Dc, nullptr, nullptr, X, X,
        512, 512, 512, 512, 512, 1, 0, 0, 0, 0, 0, 0);

    // ======== feed-forward ========
    layernorm_k<<<NTOK, 256, 0, stream>>>(X, pp[20] + (long)l * Dc, pp[21] + (long)l * Dc, TO);
    mgemm_k<4, 0, true, false, true><<<dim3(16, 32, 1), 256, 0, stream>>>(
        TO, WtL + OFF_FF1, pp[23] + (long)l * FFc, nullptr, nullptr, SCw, nullptr,
        2048, 512, 512, 512, 2048, 1, 0, 0, 0, 0, 0, 0);
    mgemm_k<4, 1, true, true, false><<<dim3(4, 32, 1), 256, 0, stream>>>(
        SCw, WtL + OFF_FF2, pp[25] + (long)l * Dc, nullptr, nullptr, X, X,
        512, 2048, 2048, 2048, 512, 1, 0, 0, 0, 0, 0, 0);
  }

  // final projection: X -> bf16 -> logits fp32 (N=500, ldc=500)
  f2b_k<<<(NTOK * Dc / 4 + 255) / 256, 256, 0, stream>>>(X, TO, (long)NTOK * Dc);
  mgemm_k<4, 1, true, false, false><<<dim3(4, 32, 1), 256, 0, stream>>>(
      TO, Wt + OFF_WOUT, b_out, nullptr, nullptr, OUT, nullptr,
      500, 512, 512, 512, 500, 1, 0, 0, 0, 0, 0, 0);
}

// Round 3
// 1305.407 us; speedup vs baseline: 4.3329x; 1.4472x over previous
//
#include <hip/hip_runtime.h>
#include <hip/hip_bf16.h>
#include <hip/hip_fp16.h>

// ---------------- problem constants ----------------
constexpr int Bc = 32, Sc = 512, Tc = 128, Dc = 512, Ac = 512, Hc = 8;
constexpr int HDc = 64, FFc = 2048, Lc = 6, Vc = 500;
constexpr int NTOK = Bc * Tc;   // 4096
constexpr int NMEM = Bc * Sc;   // 16384

typedef unsigned short u16;
typedef __attribute__((ext_vector_type(8))) short short8;  // 8 bf16 (4 VGPRs)
typedef __attribute__((ext_vector_type(4))) float f32x4;   // MFMA accumulator

__device__ __forceinline__ u16 bfc(float x) {
  __hip_bfloat16 h = __float2bfloat16(x);
  return *reinterpret_cast<u16*>(&h);
}

// async global->LDS, 16B per lane. LDS dest = wave-uniform base + lane*16.
__device__ __forceinline__ void gload16(const void* g, void* l) {
  __builtin_amdgcn_global_load_lds(
      (const __attribute__((address_space(1))) unsigned int*)g,
      (__attribute__((address_space(3))) unsigned int*)l, 16, 0, 0);
}

__device__ __forceinline__ float wave_sum(float v) {
#pragma unroll
  for (int o = 32; o > 0; o >>= 1) v += __shfl_down(v, o);
  return v;
}
__device__ __forceinline__ float wave_max(float v) {
#pragma unroll
  for (int o = 32; o > 0; o >>= 1) v = fmaxf(v, __shfl_down(v, o));
  return v;
}

// ---------------- embedding + sinusoidal PE (fp32 residual stream) ----------------
__global__ __launch_bounds__(256) void embed_pe_k(const int* __restrict__ ys,
                                                  const float* __restrict__ emb,
                                                  float* __restrict__ x) {
  int tok = blockIdx.x;
  int t = tok & (Tc - 1);
  int id = ys[tok];
  int j = threadIdx.x;
  int d0 = 2 * j;
  const float cdiv = -9.210340371976184f / (float)Dc;
  float div = expf((float)d0 * cdiv);
  float ang = (float)t * div;
  float pe0 = sinf(ang), pe1 = cosf(ang);
  const float sc = 22.627416997969522f;  // sqrt(512)
  long base = (long)tok * Dc + d0;
  long ebase = (long)id * Dc + d0;
  x[base]     = emb[ebase]     * sc + pe0;
  x[base + 1] = emb[ebase + 1] * sc + pe1;
}

// ---------------- layernorm fp32 -> bf16 ----------------
__global__ __launch_bounds__(256) void layernorm_k(const float* __restrict__ x,
                                                   const float* __restrict__ g,
                                                   const float* __restrict__ bta,
                                                   u16* __restrict__ out) {
  int row = blockIdx.x;
  int tid = threadIdx.x;
  const float* xr = x + (long)row * Dc;
  float2 xv = *(const float2*)(xr + tid * 2);
  __shared__ float red[4];
  float s = wave_sum(xv.x + xv.y);
  if ((tid & 63) == 0) red[tid >> 6] = s;
  __syncthreads();
  float mean = (red[0] + red[1] + red[2] + red[3]) * (1.0f / Dc);
  float dx0 = xv.x - mean, dx1 = xv.y - mean;
  __syncthreads();
  float s2 = wave_sum(dx0 * dx0 + dx1 * dx1);
  if ((tid & 63) == 0) red[tid >> 6] = s2;
  __syncthreads();
  float var = (red[0] + red[1] + red[2] + red[3]) * (1.0f / Dc);
  float rstd = rsqrtf(var + 1e-5f);
  ushort2 o;
  o.x = bfc(dx0 * rstd * g[2 * tid] + bta[2 * tid]);
  o.y = bfc(dx1 * rstd * g[2 * tid + 1] + bta[2 * tid + 1]);
  *(ushort2*)(out + (long)row * Dc + tid * 2) = o;
}

// ---------------- weight transpose+convert: W(K x N) fp32 -> Wt(Npad x K) bf16 ----------------
__global__ __launch_bounds__(256) void wtrans_k(const float* __restrict__ src,
                                                u16* __restrict__ dst,
                                                int K, int N, long srcStride, long dstStride) {
  int z = blockIdx.z;
  src += z * srcStride;
  dst += z * dstStride;
  __shared__ float t[32][33];
  int n0 = blockIdx.x * 32, k0 = blockIdx.y * 32;
  int tx = threadIdx.x & 31, ty = threadIdx.x >> 5;  // 32 x 8
#pragma unroll
  for (int i = 0; i < 4; i++) {
    int n = n0 + tx;
    t[ty + 8 * i][tx] = (n < N) ? src[(long)(k0 + ty + 8 * i) * N + n] : 0.0f;
  }
  __syncthreads();
#pragma unroll
  for (int i = 0; i < 4; i++) {
    dst[(long)(n0 + ty + 8 * i) * K + k0 + tx] = bfc(t[tx][ty + 8 * i]);
  }
}

// ---------------- V transpose (bf16): V[b*Scur+s][512] -> Vt[b*512+c][Scur] ----------------
__global__ __launch_bounds__(256) void vtrans_k(const u16* __restrict__ V,
                                                u16* __restrict__ Vt, int Scur) {
  int b = blockIdx.z;
  int c0 = blockIdx.x * 32, s0 = blockIdx.y * 32;
  __shared__ u16 t[32][33];
  int tx = threadIdx.x & 31, ty = threadIdx.x >> 5;
#pragma unroll
  for (int i = 0; i < 4; i++)
    t[ty + 8 * i][tx] = V[((long)b * Scur + s0 + ty + 8 * i) * 512 + c0 + tx];
  __syncthreads();
#pragma unroll
  for (int i = 0; i < 4; i++)
    Vt[((long)b * 512 + c0 + ty + 8 * i) * Scur + s0 + tx] = t[tx][ty + 8 * i];
}

// ---------------- fp32 -> bf16 convert ----------------
__global__ __launch_bounds__(256) void f2b_k(const float* __restrict__ in,
                                             u16* __restrict__ out, long n) {
  long i = ((long)blockIdx.x * 256 + threadIdx.x) * 4;
  if (i >= n) return;
  float4 v = *(const float4*)(in + i);
  ushort4 o;
  o.x = bfc(v.x); o.y = bfc(v.y); o.z = bfc(v.z); o.w = bfc(v.w);
  *(ushort4*)(out + i) = o;
}

// ---------------- bf16 MFMA GEMM (m97 structure), BM = BMW*32, BN = 128 ----------------
// C = act(A(MxK,bf16) @ Bt(NxK,bf16)^T + bias [+ R])
// 256 threads = 4 waves in 2x2. OMODE: 0 = bf16 out, 1 = fp32 out.
template <int BMW, int OMODE, bool BIAS, bool RES, bool SWISH, bool NCH>
__global__ __launch_bounds__(256) void mgemm_k(
    const u16* __restrict__ A, const u16* __restrict__ Bt,
    const float* __restrict__ bias0, const float* __restrict__ bias1,
    const float* __restrict__ bias2,
    void* __restrict__ Cv, const float* __restrict__ R,
    int N, int K, int lda, int ldb, int ldc, int nbi,
    long batAo, long batAi, long batBo, long batBi, long batCo, long batCi) {
  constexpr int BM = BMW * 32;
  int z = blockIdx.z;
  int bo = z / nbi, bi = z - bo * nbi;
  const u16* Ab = A + bo * batAo + bi * batAi;
  const u16* Bb = Bt + bo * batBo + bi * batBi;
  long coff = bo * batCo + bi * batCi;
  const float* bias = nullptr;
  if constexpr (BIAS) bias = (bi == 0) ? bias0 : ((bi == 1) ? bias1 : bias2);
  int m0 = blockIdx.y * BM, n0 = blockIdx.x * 128;

  __shared__ __align__(16) u16 As[BM * 32];
  __shared__ __align__(16) u16 Bs[128 * 32];

  int tid = threadIdx.x;
  int lane = tid & 63, wid = tid >> 6;
  int wm = wid >> 1, wn = wid & 1;
  int fr = lane & 15, grp = lane >> 4;

  f32x4 acc[BMW][4];
#pragma unroll
  for (int i = 0; i < BMW; i++)
#pragma unroll
    for (int j = 0; j < 4; j++) acc[i][j] = (f32x4){0.f, 0.f, 0.f, 0.f};

  const u16* ga = Ab + (long)(m0 + (tid >> 2)) * lda + ((tid & 3) << 3);
  const u16* gb = Bb + (long)(n0 + (tid >> 2)) * ldb + ((tid & 3) << 3);
  u16* lA = &As[tid * 8];
  u16* lB = &Bs[tid * 8];

  for (int kt = 0; kt < K; kt += 32) {
    gload16(ga + kt, lA);
    if constexpr (BM == 128) gload16(ga + kt + (long)64 * lda, lA + 2048);
    gload16(gb + kt, lB);
    gload16(gb + kt + (long)64 * ldb, lB + 2048);
    __syncthreads();
    short8 av[BMW], bv[4];
#pragma unroll
    for (int i = 0; i < BMW; i++)
      av[i] = *(const short8*)&As[(wm * BMW * 16 + i * 16 + fr) * 32 + grp * 8];
#pragma unroll
    for (int j = 0; j < 4; j++)
      bv[j] = *(const short8*)&Bs[(wn * 64 + j * 16 + fr) * 32 + grp * 8];
#pragma unroll
    for (int i = 0; i < BMW; i++)
#pragma unroll
      for (int j = 0; j < 4; j++)
        acc[i][j] = __builtin_amdgcn_mfma_f32_16x16x32_bf16(av[i], bv[j], acc[i][j], 0, 0, 0);
    __syncthreads();
  }

  int rbase = m0 + wm * BMW * 16 + grp * 4;
  int cbase = n0 + wn * 64 + fr;
#pragma unroll
  for (int i = 0; i < BMW; i++) {
#pragma unroll
    for (int j = 0; j < 4; j++) {
      int col = cbase + j * 16;
      if (NCH && col >= N) continue;
      float bb = 0.0f;
      if constexpr (BIAS) bb = bias[col];
#pragma unroll
      for (int r = 0; r < 4; r++) {
        int row = rbase + i * 16 + r;
        float v = acc[i][j][r] + bb;
        long idx = coff + (long)row * ldc + col;
        if constexpr (RES) v += R[idx];
        if constexpr (SWISH) v = v / (1.0f + expf(-v));
        if constexpr (OMODE == 0) ((u16*)Cv)[idx] = bfc(v);
        else ((float*)Cv)[idx] = v;
      }
    }
  }
}

// ---------------- fused flash attention ----------------
// One wg per (b,h): 256 thr = 4 waves; wave owns 32 q rows (q = wid*32 + i*16 + ...).
// Q/K: token-major [.,512] bf16 (col = h*64+d); Vt: [b][512][SKV]; O: [token][512].
// CAUSAL: kv <= t and kv < len[b]; else kv < len[b].
template <int SKV, int KVBLK, bool CAUSAL>
__global__ __launch_bounds__(256) void fattn_k(
    const u16* __restrict__ Q, const u16* __restrict__ Kg, const u16* __restrict__ Vtg,
    u16* __restrict__ O, const int* __restrict__ lens) {
  constexpr int NJ  = KVBLK / 16;   // S col fragments per tile
  constexpr int NKV = KVBLK / 32;   // PV k-steps per tile
  constexpr int NT  = SKV / KVBLK;  // tiles
  constexpr int KST = 72;           // K lds row stride (u16), padded
  constexpr int VST = KVBLK + 8;    // Vt / P lds row stride (u16), padded
  constexpr int CHK = KVBLK * 8 / 256;        // 16B chunks per thread for K tile
  constexpr int CHV = 64 * (KVBLK / 8) / 256; // and for Vt tile

  __shared__ __align__(16) u16 Ks[KVBLK * KST];
  __shared__ __align__(16) u16 Vs[64 * VST];
  __shared__ __align__(16) u16 Ps[128 * VST];

  int bh = blockIdx.x; int b = bh >> 3, h = bh & 7;
  int tid = threadIdx.x, lane = tid & 63, wid = tid >> 6;
  int fr = lane & 15, grp = lane >> 4;
  int len = lens[b];

  // Q fragments: row = wid*32 + i*16 + fr, elems d = k2*32 + grp*8
  short8 qa[2][2];
  {
    const u16* qp = Q + ((long)b * Tc + wid * 32 + fr) * 512 + h * 64 + grp * 8;
#pragma unroll
    for (int i = 0; i < 2; i++)
#pragma unroll
      for (int k2 = 0; k2 < 2; k2++)
        qa[i][k2] = *(const short8*)(qp + (long)i * 16 * 512 + k2 * 32);
  }

  float m_run[2][4], l_run[2][4];
  f32x4 acc_o[2][4];
#pragma unroll
  for (int i = 0; i < 2; i++)
#pragma unroll
    for (int r = 0; r < 4; r++) { m_run[i][r] = -1e30f; l_run[i][r] = 0.0f; }
#pragma unroll
  for (int i = 0; i < 2; i++)
#pragma unroll
    for (int j = 0; j < 4; j++) acc_o[i][j] = (f32x4){0.f, 0.f, 0.f, 0.f};

  const u16* Kbase = Kg + ((long)b * SKV) * 512 + h * 64;
  const u16* Vbase = Vtg + ((long)b * 512 + h * 64) * SKV;

  short8 kreg[CHK], vreg[CHV];
  // preload tile 0
#pragma unroll
  for (int c = 0; c < CHK; c++) {
    int idx = tid + 256 * c; int kv = idx >> 3, s = idx & 7;
    kreg[c] = *(const short8*)(Kbase + (long)kv * 512 + s * 8);
  }
#pragma unroll
  for (int c = 0; c < CHV; c++) {
    int idx = tid + 256 * c; int d = idx / (KVBLK / 8), sk = idx % (KVBLK / 8);
    vreg[c] = *(const short8*)(Vbase + (long)d * SKV + sk * 8);
  }

  for (int t = 0; t < NT; t++) {
    int kv0 = t * KVBLK;
    __syncthreads();  // prior-tile LDS reads done (all waves)
#pragma unroll
    for (int c = 0; c < CHK; c++) {
      int idx = tid + 256 * c; int kv = idx >> 3, s = idx & 7;
      *(short8*)&Ks[kv * KST + s * 8] = kreg[c];
    }
#pragma unroll
    for (int c = 0; c < CHV; c++) {
      int idx = tid + 256 * c; int d = idx / (KVBLK / 8), sk = idx % (KVBLK / 8);
      *(short8*)&Vs[d * VST + sk * 8] = vreg[c];
    }
    __syncthreads();  // LDS ready
    // prefetch next tile into regs (overlaps with compute below)
    if (t + 1 < NT) {
      int kvn = kv0 + KVBLK;
#pragma unroll
      for (int c = 0; c < CHK; c++) {
        int idx = tid + 256 * c; int kv = idx >> 3, s = idx & 7;
        kreg[c] = *(const short8*)(Kbase + (long)(kvn + kv) * 512 + s * 8);
      }
#pragma unroll
      for (int c = 0; c < CHV; c++) {
        int idx = tid + 256 * c; int d = idx / (KVBLK / 8), sk = idx % (KVBLK / 8);
        vreg[c] = *(const short8*)(Vbase + (long)d * SKV + kvn + sk * 8);
      }
    }

    int jmax = NJ;
    if constexpr (CAUSAL) jmax = (wid * 32 + 31 - kv0) / 16 + 1;  // wave-uniform

    // ---- S = Q @ K^T ----
    f32x4 accs[2][NJ];
#pragma unroll
    for (int j = 0; j < NJ; j++) {
      if (CAUSAL && j >= jmax) continue;
      short8 bv0 = *(const short8*)&Ks[(j * 16 + fr) * KST + grp * 8];
      short8 bv1 = *(const short8*)&Ks[(j * 16 + fr) * KST + 32 + grp * 8];
#pragma unroll
      for (int i = 0; i < 2; i++) {
        f32x4 a = __builtin_amdgcn_mfma_f32_16x16x32_bf16(qa[i][0], bv0, (f32x4){0.f,0.f,0.f,0.f}, 0, 0, 0);
        accs[i][j] = __builtin_amdgcn_mfma_f32_16x16x32_bf16(qa[i][1], bv1, a, 0, 0, 0);
      }
    }

    // ---- online softmax ----
    float alpha[2][4];
#pragma unroll
    for (int i = 0; i < 2; i++) {
#pragma unroll
      for (int r = 0; r < 4; r++) {
        int qrow = wid * 32 + i * 16 + grp * 4 + r;
        float vmax = -1e30f;
#pragma unroll
        for (int j = 0; j < NJ; j++) {
          if (CAUSAL && j >= jmax) continue;
          int kvb = kv0 + j * 16 + fr;
          float s = accs[i][j][r] * 0.125f;
          bool msk = (kvb >= len) || (CAUSAL && kvb > qrow);
          s = msk ? -1e30f : s;
          accs[i][j][r] = s;
          vmax = fmaxf(vmax, s);
        }
        vmax = fmaxf(vmax, __shfl_xor(vmax, 1));
        vmax = fmaxf(vmax, __shfl_xor(vmax, 2));
        vmax = fmaxf(vmax, __shfl_xor(vmax, 4));
        vmax = fmaxf(vmax, __shfl_xor(vmax, 8));
        float mn = fmaxf(m_run[i][r], vmax);
        float al = __expf(m_run[i][r] - mn);
        m_run[i][r] = mn;
        alpha[i][r] = al;
        float rs = 0.0f;
#pragma unroll
        for (int j = 0; j < NJ; j++) {
          if (CAUSAL && j >= jmax) continue;
          float p = __expf(accs[i][j][r] - mn);
          accs[i][j][r] = p;
          rs += p;
        }
        rs += __shfl_xor(rs, 1);
        rs += __shfl_xor(rs, 2);
        rs += __shfl_xor(rs, 4);
        rs += __shfl_xor(rs, 8);
        l_run[i][r] = l_run[i][r] * al + rs;
      }
    }

    // ---- write P (bf16) to per-wave LDS region ----
#pragma unroll
    for (int i = 0; i < 2; i++)
#pragma unroll
      for (int j = 0; j < NJ; j++) {
        if (CAUSAL && j >= jmax) continue;
#pragma unroll
        for (int r = 0; r < 4; r++) {
          int prow = wid * 32 + i * 16 + grp * 4 + r;
          Ps[prow * VST + j * 16 + fr] = bfc(accs[i][j][r]);
        }
      }

    // ---- rescale O ----
#pragma unroll
    for (int i = 0; i < 2; i++)
#pragma unroll
      for (int jd = 0; jd < 4; jd++)
#pragma unroll
        for (int r = 0; r < 4; r++)
          acc_o[i][jd][r] *= alpha[i][r];

    // ---- O += P @ V ----
    int kvmax = NKV;
    if constexpr (CAUSAL) kvmax = wid + 1;
#pragma unroll
    for (int kk = 0; kk < NKV; kk++) {
      if (CAUSAL && kk >= kvmax) continue;
      short8 pa[2];
#pragma unroll
      for (int i = 0; i < 2; i++)
        pa[i] = *(const short8*)&Ps[(wid * 32 + i * 16 + fr) * VST + kk * 32 + grp * 8];
#pragma unroll
      for (int jd = 0; jd < 4; jd++) {
        short8 vb = *(const short8*)&Vs[(jd * 16 + fr) * VST + kk * 32 + grp * 8];
#pragma unroll
        for (int i = 0; i < 2; i++)
          acc_o[i][jd] = __builtin_amdgcn_mfma_f32_16x16x32_bf16(pa[i], vb, acc_o[i][jd], 0, 0, 0);
      }
    }
  }

  // ---- finalize: O / l ----
#pragma unroll
  for (int i = 0; i < 2; i++) {
#pragma unroll
    for (int r = 0; r < 4; r++) {
      float inv = 1.0f / l_run[i][r];
      long tok = (long)b * Tc + wid * 32 + i * 16 + grp * 4 + r;
#pragma unroll
      for (int jd = 0; jd < 4; jd++)
        O[tok * 512 + h * 64 + jd * 16 + fr] = bfc(acc_o[i][jd][r] * inv);
    }
  }
}

// ---------------- host launcher ----------------
extern "C" void kernel_launch(void* const* d_in, const int* in_sizes, int n_in,
                              void* d_out, int out_size, void* d_ws, size_t ws_size,
                              hipStream_t stream) {
  const float* memory   = (const float*)d_in[0];
  const int*   mem_lens = (const int*)d_in[1];
  const int*   ys       = (const int*)d_in[2];
  const int*   ys_lens  = (const int*)d_in[3];
  const float* emb      = (const float*)d_in[4];
  const float* w_out    = (const float*)d_in[5];
  const float* b_out    = (const float*)d_in[6];
  const float* pp[26];
  for (int i = 0; i < 26; i++) pp[i] = (const float*)d_in[7 + i];

  // ---- ws layout ----
  constexpr long PLW = 4194304;  // bf16 elems of transposed weights per layer
  constexpr long OFF_SAQ = 0, OFF_SAK = 262144, OFF_SAV = 524288, OFF_SAO = 786432,
                 OFF_CAQ = 1048576, OFF_CAK = 1310720, OFF_CAV = 1572864,
                 OFF_CAO = 1835008, OFF_FF1 = 2097152, OFF_FF2 = 3145728,
                 OFF_WOUT = 6 * PLW;
  u16*   Wt   = (u16*)d_ws;                          // 25,427,968 u16
  float* X    = (float*)(Wt + 25427968);             // 2,097,152 f32
  u16*   TO   = (u16*)(X + 2097152);                 // 2,097,152 bf16
  u16*   QKV  = TO + 2097152;                        // 3 x 2,097,152 bf16
  u16*   memb = QKV + 3 * 2097152;                   // 8,388,608 bf16
  u16*   Kb   = memb + 8388608;                      // 8,388,608 bf16 (cross K)
  u16*   SCw  = Kb + 8388608;                        // 16,777,216 (Vtmp / FFH)
  u16*   Vt   = SCw + 16777216;                      // 8,388,608 bf16
  float* OUT  = (float*)d_out;

  auto WT = [&](const float* src, long dstoff, int K, int N, int Npad, int Lz,
                long srcStride, long dstStride) {
    dim3 g(Npad / 32, K / 32, Lz);
    wtrans_k<<<g, 256, 0, stream>>>(src, Wt + dstoff, K, N, srcStride, dstStride);
  };
  WT(pp[2],  OFF_SAQ, 512, 512, 512, Lc, 262144, PLW);
  WT(pp[4],  OFF_SAK, 512, 512, 512, Lc, 262144, PLW);
  WT(pp[6],  OFF_SAV, 512, 512, 512, Lc, 262144, PLW);
  WT(pp[8],  OFF_SAO, 512, 512, 512, Lc, 262144, PLW);
  WT(pp[12], OFF_CAQ, 512, 512, 512, Lc, 262144, PLW);
  WT(pp[14], OFF_CAK, 512, 512, 512, Lc, 262144, PLW);
  WT(pp[16], OFF_CAV, 512, 512, 512, Lc, 262144, PLW);
  WT(pp[18], OFF_CAO, 512, 512, 512, Lc, 262144, PLW);
  WT(pp[22], OFF_FF1, 512, 2048, 2048, Lc, 1048576, PLW);
  WT(pp[24], OFF_FF2, 2048, 512, 512, Lc, 1048576, PLW);
  WT(w_out,  OFF_WOUT, 512, 500, 512, 1, 0, 0);

  f2b_k<<<(NMEM * Dc / 4 + 255) / 256, 256, 0, stream>>>(memory, memb, (long)NMEM * Dc);
  embed_pe_k<<<NTOK, 256, 0, stream>>>(ys, emb, X);

  for (int l = 0; l < Lc; l++) {
    const u16* WtL = Wt + (long)l * PLW;

    // ======== self-attention ========
    layernorm_k<<<NTOK, 256, 0, stream>>>(X, pp[0] + (long)l * Dc, pp[1] + (long)l * Dc, TO);
    mgemm_k<2, 0, true, false, false, false><<<dim3(4, 64, 3), 256, 0, stream>>>(
        TO, WtL + OFF_SAQ, pp[3] + (long)l * Ac, pp[5] + (long)l * Ac, pp[7] + (long)l * Ac,
        QKV, nullptr, 512, 512, 512, 512, 512, 3, 0, 0, 0, 262144, 0, 2097152);
    vtrans_k<<<dim3(16, 4, Bc), 256, 0, stream>>>(QKV + 2 * 2097152, Vt, Tc);
    fattn_k<128, 128, true><<<256, 256, 0, stream>>>(
        QKV, QKV + 2097152, Vt, TO, ys_lens);
    mgemm_k<2, 1, true, true, false, false><<<dim3(4, 64, 1), 256, 0, stream>>>(
        TO, WtL + OFF_SAO, pp[9] + (long)l * Dc, nullptr, nullptr, X, X,
        512, 512, 512, 512, 512, 1, 0, 0, 0, 0, 0, 0);

    // ======== cross-attention ========
    layernorm_k<<<NTOK, 256, 0, stream>>>(X, pp[10] + (long)l * Dc, pp[11] + (long)l * Dc, TO);
    mgemm_k<2, 0, true, false, false, false><<<dim3(4, 64, 1), 256, 0, stream>>>(
        TO, WtL + OFF_CAQ, pp[13] + (long)l * Ac, nullptr, nullptr, QKV, nullptr,
        512, 512, 512, 512, 512, 1, 0, 0, 0, 0, 0, 0);
    mgemm_k<4, 0, true, false, false, false><<<dim3(4, 128, 2), 256, 0, stream>>>(
        memb, WtL + OFF_CAK, pp[15] + (long)l * Ac, pp[17] + (long)l * Ac, nullptr,
        Kb, nullptr, 512, 512, 512, 512, 512, 2, 0, 0, 0, 262144, 0, 8388608);
    vtrans_k<<<dim3(16, 16, Bc), 256, 0, stream>>>(SCw, Vt, Sc);
    fattn_k<512, 64, false><<<256, 256, 0, stream>>>(
        QKV, Kb, Vt, TO, mem_lens);
    mgemm_k<2, 1, true, true, false, false><<<dim3(4, 64, 1), 256, 0, stream>>>(
        TO, WtL + OFF_CAO, pp[19] + (long)l * Dc, nullptr, nullptr, X, X,
        512, 512, 512, 512, 512, 1, 0, 0, 0, 0, 0, 0);

    // ======== feed-forward ========
    layernorm_k<<<NTOK, 256, 0, stream>>>(X, pp[20] + (long)l * Dc, pp[21] + (long)l * Dc, TO);
    mgemm_k<2, 0, true, false, true, false><<<dim3(16, 64, 1), 256, 0, stream>>>(
        TO, WtL + OFF_FF1, pp[23] + (long)l * FFc, nullptr, nullptr, SCw, nullptr,
        2048, 512, 512, 512, 2048, 1, 0, 0, 0, 0, 0, 0);
    mgemm_k<2, 1, true, true, false, false><<<dim3(4, 64, 1), 256, 0, stream>>>(
        SCw, WtL + OFF_FF2, pp[25] + (long)l * Dc, nullptr, nullptr, X, X,
        512, 2048, 2048, 2048, 512, 1, 0, 0, 0, 0, 0, 0);
  }

  // final projection: X -> bf16 -> logits fp32 (N=500, ldc=500)
  f2b_k<<<(NTOK * Dc / 4 + 255) / 256, 256, 0, stream>>>(X, TO, (long)NTOK * Dc);
  mgemm_k<2, 1, true, false, false, true><<<dim3(4, 64, 1), 256, 0, stream>>>(
      TO, Wt + OFF_WOUT, b_out, nullptr, nullptr, OUT, nullptr,
      500, 512, 512, 512, 500, 1, 0, 0, 0, 0, 0, 0);
}

// Round 4
// 1252.173 us; speedup vs baseline: 4.5171x; 1.0425x over previous
//
#include <hip/hip_runtime.h>
#include <hip/hip_bf16.h>
#include <hip/hip_fp16.h>

// ---------------- problem constants ----------------
constexpr int Bc = 32, Sc = 512, Tc = 128, Dc = 512, Ac = 512, Hc = 8;
constexpr int HDc = 64, FFc = 2048, Lc = 6, Vc = 500;
constexpr int NTOK = Bc * Tc;   // 4096
constexpr int NMEM = Bc * Sc;   // 16384

typedef unsigned short u16;
typedef __attribute__((ext_vector_type(8))) short short8;  // 8 bf16 (4 VGPRs)
typedef __attribute__((ext_vector_type(4))) float f32x4;   // MFMA accumulator

__device__ __forceinline__ u16 bfc(float x) {
  __hip_bfloat16 h = __float2bfloat16(x);
  return *reinterpret_cast<u16*>(&h);
}

// async global->LDS, 16B per lane. LDS dest = wave-uniform base + lane*16.
__device__ __forceinline__ void gload16(const void* g, void* l) {
  __builtin_amdgcn_global_load_lds(
      (const __attribute__((address_space(1))) unsigned int*)g,
      (__attribute__((address_space(3))) unsigned int*)l, 16, 0, 0);
}

__device__ __forceinline__ float wave_sum(float v) {
#pragma unroll
  for (int o = 32; o > 0; o >>= 1) v += __shfl_down(v, o);
  return v;
}
__device__ __forceinline__ float wave_max(float v) {
#pragma unroll
  for (int o = 32; o > 0; o >>= 1) v = fmaxf(v, __shfl_down(v, o));
  return v;
}

// ---------------- embedding + sinusoidal PE (fp32 residual stream) ----------------
__global__ __launch_bounds__(256) void embed_pe_k(const int* __restrict__ ys,
                                                  const float* __restrict__ emb,
                                                  float* __restrict__ x) {
  int tok = blockIdx.x;
  int t = tok & (Tc - 1);
  int id = ys[tok];
  int j = threadIdx.x;
  int d0 = 2 * j;
  const float cdiv = -9.210340371976184f / (float)Dc;
  float div = expf((float)d0 * cdiv);
  float ang = (float)t * div;
  float pe0 = sinf(ang), pe1 = cosf(ang);
  const float sc = 22.627416997969522f;  // sqrt(512)
  long base = (long)tok * Dc + d0;
  long ebase = (long)id * Dc + d0;
  x[base]     = emb[ebase]     * sc + pe0;
  x[base + 1] = emb[ebase + 1] * sc + pe1;
}

// ---------------- layernorm fp32 -> bf16 ----------------
__global__ __launch_bounds__(256) void layernorm_k(const float* __restrict__ x,
                                                   const float* __restrict__ g,
                                                   const float* __restrict__ bta,
                                                   u16* __restrict__ out) {
  int row = blockIdx.x;
  int tid = threadIdx.x;
  const float* xr = x + (long)row * Dc;
  float2 xv = *(const float2*)(xr + tid * 2);
  __shared__ float red[4];
  float s = wave_sum(xv.x + xv.y);
  if ((tid & 63) == 0) red[tid >> 6] = s;
  __syncthreads();
  float mean = (red[0] + red[1] + red[2] + red[3]) * (1.0f / Dc);
  float dx0 = xv.x - mean, dx1 = xv.y - mean;
  __syncthreads();
  float s2 = wave_sum(dx0 * dx0 + dx1 * dx1);
  if ((tid & 63) == 0) red[tid >> 6] = s2;
  __syncthreads();
  float var = (red[0] + red[1] + red[2] + red[3]) * (1.0f / Dc);
  float rstd = rsqrtf(var + 1e-5f);
  ushort2 o;
  o.x = bfc(dx0 * rstd * g[2 * tid] + bta[2 * tid]);
  o.y = bfc(dx1 * rstd * g[2 * tid + 1] + bta[2 * tid + 1]);
  *(ushort2*)(out + (long)row * Dc + tid * 2) = o;
}

// ---------------- weight transpose+convert: W(K x N) fp32 -> Wt(Npad x K) bf16 ----------------
__global__ __launch_bounds__(256) void wtrans_k(const float* __restrict__ src,
                                                u16* __restrict__ dst,
                                                int K, int N, long srcStride, long dstStride) {
  int z = blockIdx.z;
  src += z * srcStride;
  dst += z * dstStride;
  __shared__ float t[32][33];
  int n0 = blockIdx.x * 32, k0 = blockIdx.y * 32;
  int tx = threadIdx.x & 31, ty = threadIdx.x >> 5;  // 32 x 8
#pragma unroll
  for (int i = 0; i < 4; i++) {
    int n = n0 + tx;
    t[ty + 8 * i][tx] = (n < N) ? src[(long)(k0 + ty + 8 * i) * N + n] : 0.0f;
  }
  __syncthreads();
#pragma unroll
  for (int i = 0; i < 4; i++) {
    dst[(long)(n0 + ty + 8 * i) * K + k0 + tx] = bfc(t[tx][ty + 8 * i]);
  }
}

// ---------------- fp32 -> bf16 convert ----------------
__global__ __launch_bounds__(256) void f2b_k(const float* __restrict__ in,
                                             u16* __restrict__ out, long n) {
  long i = ((long)blockIdx.x * 256 + threadIdx.x) * 4;
  if (i >= n) return;
  float4 v = *(const float4*)(in + i);
  ushort4 o;
  o.x = bfc(v.x); o.y = bfc(v.y); o.z = bfc(v.z); o.w = bfc(v.w);
  *(ushort4*)(out + i) = o;
}

// ---------------- bf16 MFMA GEMM, 2-phase prefetch (T3-minimum), BM = BMW*32, BN = 128 --------
// C = act(A(MxK,bf16) @ Bt(NxK,bf16)^T + bias [+ R])
// 256 threads = 4 waves in 2x2. Double-buffered LDS; stage(next) issued BEFORE
// compute(current); ONE __syncthreads per K-step (implicit vmcnt(0)+lgkmcnt(0) drain).
// OMODE: 0 = bf16 out, 1 = fp32 out.
template <int BMW, int OMODE, bool BIAS, bool RES, bool SWISH, bool NCH>
__global__ __launch_bounds__(256) void mgemm_k(
    const u16* __restrict__ A, const u16* __restrict__ Bt,
    const float* __restrict__ bias0, const float* __restrict__ bias1,
    const float* __restrict__ bias2,
    void* __restrict__ Cv, const float* __restrict__ R,
    int N, int K, int lda, int ldb, int ldc, int nbi,
    long batAo, long batAi, long batBo, long batBi, long batCo, long batCi) {
  constexpr int BM = BMW * 32;
  int z = blockIdx.z;
  int bo = z / nbi, bi = z - bo * nbi;
  const u16* Ab = A + bo * batAo + bi * batAi;
  const u16* Bb = Bt + bo * batBo + bi * batBi;
  long coff = bo * batCo + bi * batCi;
  const float* bias = nullptr;
  if constexpr (BIAS) bias = (bi == 0) ? bias0 : ((bi == 1) ? bias1 : bias2);
  int m0 = blockIdx.y * BM, n0 = blockIdx.x * 128;

  __shared__ __align__(16) u16 As[2][BM * 32];
  __shared__ __align__(16) u16 Bs[2][128 * 32];

  int tid = threadIdx.x;
  int lane = tid & 63, wid = tid >> 6;
  int wm = wid >> 1, wn = wid & 1;
  int fr = lane & 15, grp = lane >> 4;

  f32x4 acc[BMW][4];
#pragma unroll
  for (int i = 0; i < BMW; i++)
#pragma unroll
    for (int j = 0; j < 4; j++) acc[i][j] = (f32x4){0.f, 0.f, 0.f, 0.f};

  const u16* ga = Ab + (long)(m0 + (tid >> 2)) * lda + ((tid & 3) << 3);
  const u16* gb = Bb + (long)(n0 + (tid >> 2)) * ldb + ((tid & 3) << 3);

  auto STAGE = [&](int buf, int kt) {
    u16* lA = &As[buf][tid * 8];
    u16* lB = &Bs[buf][tid * 8];
    gload16(ga + kt, lA);
    if constexpr (BM == 128) gload16(ga + kt + (long)64 * lda, lA + 2048);
    gload16(gb + kt, lB);
    gload16(gb + kt + (long)64 * ldb, lB + 2048);
  };

  auto COMPUTE = [&](int buf) {
    short8 av[BMW], bv[4];
#pragma unroll
    for (int i = 0; i < BMW; i++)
      av[i] = *(const short8*)&As[buf][(wm * BMW * 16 + i * 16 + fr) * 32 + grp * 8];
#pragma unroll
    for (int j = 0; j < 4; j++)
      bv[j] = *(const short8*)&Bs[buf][(wn * 64 + j * 16 + fr) * 32 + grp * 8];
#pragma unroll
    for (int i = 0; i < BMW; i++)
#pragma unroll
      for (int j = 0; j < 4; j++)
        acc[i][j] = __builtin_amdgcn_mfma_f32_16x16x32_bf16(av[i], bv[j], acc[i][j], 0, 0, 0);
  };

  STAGE(0, 0);
  __syncthreads();          // vmcnt(0) drain + barrier: tile 0 resident
  int cur = 0;
  for (int kt = 32; kt < K; kt += 32) {
    STAGE(cur ^ 1, kt);     // issue next-tile loads first: latency hides under MFMA
    COMPUTE(cur);
    __syncthreads();        // staged writes landed + all reads of 'cur' retired
    cur ^= 1;
  }
  COMPUTE(cur);             // last tile, no prefetch

  int rbase = m0 + wm * BMW * 16 + grp * 4;
  int cbase = n0 + wn * 64 + fr;
#pragma unroll
  for (int i = 0; i < BMW; i++) {
#pragma unroll
    for (int j = 0; j < 4; j++) {
      int col = cbase + j * 16;
      if (NCH && col >= N) continue;
      float bb = 0.0f;
      if constexpr (BIAS) bb = bias[col];
#pragma unroll
      for (int r = 0; r < 4; r++) {
        int row = rbase + i * 16 + r;
        float v = acc[i][j][r] + bb;
        long idx = coff + (long)row * ldc + col;
        if constexpr (RES) v += R[idx];
        if constexpr (SWISH) v = v / (1.0f + expf(-v));
        if constexpr (OMODE == 0) ((u16*)Cv)[idx] = bfc(v);
        else ((float*)Cv)[idx] = v;
      }
    }
  }
}

// ---------------- fused flash attention ----------------
// Grid (b*H, qb). 256 thr = 4 waves; each wave owns WR=16*IQ q rows.
// Q/K/V all token-major [.,512] bf16 (col = h*64+d); V transposed into LDS at staging.
// O: [token][512]. CAUSAL requires IQ==2 (jmax*16 == kvmax*32 alignment).
template <int SKV, int KVBLK, bool CAUSAL, int IQ>
__global__ __launch_bounds__(256) void fattn_k(
    const u16* __restrict__ Q, const u16* __restrict__ Kg, const u16* __restrict__ Vg,
    u16* __restrict__ O, const int* __restrict__ lens) {
  constexpr int NJ  = KVBLK / 16;   // S col fragments per tile
  constexpr int NKV = KVBLK / 32;   // PV k-steps per tile
  constexpr int NT  = SKV / KVBLK;  // tiles
  constexpr int KST = 72;           // K lds row stride (u16), padded
  constexpr int VST = KVBLK + 8;    // Vt / P lds row stride (u16), padded
  constexpr int WR  = 16 * IQ;      // q rows per wave
  constexpr int WGR = 64 * IQ;      // q rows per workgroup
  constexpr int CH  = KVBLK / 32;   // 16B chunks per thread for K tile (= V tile)

  __shared__ __align__(16) u16 Ks[KVBLK * KST];
  __shared__ __align__(16) u16 Vs[64 * VST];
  __shared__ __align__(16) u16 Ps[WGR * VST];

  int bh = blockIdx.x; int b = bh >> 3, h = bh & 7;
  int row00 = blockIdx.y * WGR;
  int tid = threadIdx.x, lane = tid & 63, wid = tid >> 6;
  int fr = lane & 15, grp = lane >> 4;
  int len = lens[b];
  int row0w = row00 + wid * WR;

  // Q fragments: row = row0w + i*16 + fr, elems d = k2*32 + grp*8
  short8 qa[IQ][2];
  {
    const u16* qp = Q + ((long)b * Tc + row0w + fr) * 512 + h * 64 + grp * 8;
#pragma unroll
    for (int i = 0; i < IQ; i++)
#pragma unroll
      for (int k2 = 0; k2 < 2; k2++)
        qa[i][k2] = *(const short8*)(qp + (long)i * 16 * 512 + k2 * 32);
  }

  float m_run[IQ][4], l_run[IQ][4];
  f32x4 acc_o[IQ][4];
#pragma unroll
  for (int i = 0; i < IQ; i++)
#pragma unroll
    for (int r = 0; r < 4; r++) { m_run[i][r] = -1e30f; l_run[i][r] = 0.0f; }
#pragma unroll
  for (int i = 0; i < IQ; i++)
#pragma unroll
    for (int j = 0; j < 4; j++) acc_o[i][j] = (f32x4){0.f, 0.f, 0.f, 0.f};

  const u16* Kbase = Kg + ((long)b * SKV) * 512 + h * 64;
  const u16* Vbase = Vg + ((long)b * SKV) * 512 + h * 64;

  // tile count: causal bound (wg-uniform) and len bound (wg-uniform)
  int NTeff = NT;
  if constexpr (CAUSAL) NTeff = (row00 + WGR - 1) / KVBLK + 1;
  int lenT = (len + KVBLK - 1) / KVBLK;   // tiles wholly beyond len contribute 0
  if (lenT < NTeff) NTeff = lenT;

  short8 kreg[CH], vreg[CH];
  // preload tile 0 (K rows coalesced; V rows coalesced, transposed at LDS write)
#pragma unroll
  for (int c = 0; c < CH; c++) {
    int idx = tid + 256 * c; int kv = idx >> 3, s = idx & 7;
    kreg[c] = *(const short8*)(Kbase + (long)kv * 512 + s * 8);
    vreg[c] = *(const short8*)(Vbase + (long)kv * 512 + s * 8);
  }

  for (int t = 0; t < NTeff; t++) {
    int kv0 = t * KVBLK;
    __syncthreads();  // prior-tile LDS reads done (all waves)
#pragma unroll
    for (int c = 0; c < CH; c++) {
      int idx = tid + 256 * c; int kv = idx >> 3, s = idx & 7;
      *(short8*)&Ks[kv * KST + s * 8] = kreg[c];
#pragma unroll
      for (int j = 0; j < 8; j++)
        Vs[(s * 8 + j) * VST + kv] = (u16)vreg[c][j];   // transpose: Vs[d][kv]
    }
    __syncthreads();  // LDS ready
    // prefetch next tile into regs (overlaps with compute below)
    if (t + 1 < NTeff) {
      int kvn = kv0 + KVBLK;
#pragma unroll
      for (int c = 0; c < CH; c++) {
        int idx = tid + 256 * c; int kv = idx >> 3, s = idx & 7;
        kreg[c] = *(const short8*)(Kbase + (long)(kvn + kv) * 512 + s * 8);
        vreg[c] = *(const short8*)(Vbase + (long)(kvn + kv) * 512 + s * 8);
      }
    }

    int jmax = NJ;
    if constexpr (CAUSAL) {
      jmax = (row0w + WR - 1 - kv0) / 16 + 1;  // wave-uniform
      if (jmax > NJ) jmax = NJ;
    }

    // ---- S = Q @ K^T ----
    f32x4 accs[IQ][NJ];
#pragma unroll
    for (int j = 0; j < NJ; j++) {
      if (CAUSAL && j >= jmax) continue;
      short8 bv0 = *(const short8*)&Ks[(j * 16 + fr) * KST + grp * 8];
      short8 bv1 = *(const short8*)&Ks[(j * 16 + fr) * KST + 32 + grp * 8];
#pragma unroll
      for (int i = 0; i < IQ; i++) {
        f32x4 a = __builtin_amdgcn_mfma_f32_16x16x32_bf16(qa[i][0], bv0, (f32x4){0.f,0.f,0.f,0.f}, 0, 0, 0);
        accs[i][j] = __builtin_amdgcn_mfma_f32_16x16x32_bf16(qa[i][1], bv1, a, 0, 0, 0);
      }
    }

    // ---- online softmax ----
    float alpha[IQ][4];
#pragma unroll
    for (int i = 0; i < IQ; i++) {
#pragma unroll
      for (int r = 0; r < 4; r++) {
        int qrow = row0w + i * 16 + grp * 4 + r;
        float vmax = -1e30f;
#pragma unroll
        for (int j = 0; j < NJ; j++) {
          if (CAUSAL && j >= jmax) continue;
          int kvb = kv0 + j * 16 + fr;
          float s = accs[i][j][r] * 0.125f;
          bool msk = (kvb >= len) || (CAUSAL && kvb > qrow);
          s = msk ? -1e30f : s;
          accs[i][j][r] = s;
          vmax = fmaxf(vmax, s);
        }
        vmax = fmaxf(vmax, __shfl_xor(vmax, 1));
        vmax = fmaxf(vmax, __shfl_xor(vmax, 2));
        vmax = fmaxf(vmax, __shfl_xor(vmax, 4));
        vmax = fmaxf(vmax, __shfl_xor(vmax, 8));
        float mn = fmaxf(m_run[i][r], vmax);
        float al = __expf(m_run[i][r] - mn);
        m_run[i][r] = mn;
        alpha[i][r] = al;
        float rs = 0.0f;
#pragma unroll
        for (int j = 0; j < NJ; j++) {
          if (CAUSAL && j >= jmax) continue;
          float p = __expf(accs[i][j][r] - mn);
          accs[i][j][r] = p;
          rs += p;
        }
        rs += __shfl_xor(rs, 1);
        rs += __shfl_xor(rs, 2);
        rs += __shfl_xor(rs, 4);
        rs += __shfl_xor(rs, 8);
        l_run[i][r] = l_run[i][r] * al + rs;
      }
    }

    // ---- write P (bf16) to per-wave LDS region ----
#pragma unroll
    for (int i = 0; i < IQ; i++)
#pragma unroll
      for (int j = 0; j < NJ; j++) {
        if (CAUSAL && j >= jmax) continue;
#pragma unroll
        for (int r = 0; r < 4; r++) {
          int prow = wid * WR + i * 16 + grp * 4 + r;
          Ps[prow * VST + j * 16 + fr] = bfc(accs[i][j][r]);
        }
      }

    // ---- rescale O ----
#pragma unroll
    for (int i = 0; i < IQ; i++)
#pragma unroll
      for (int jd = 0; jd < 4; jd++)
#pragma unroll
        for (int r = 0; r < 4; r++)
          acc_o[i][jd][r] *= alpha[i][r];

    // ---- O += P @ V ----
    int kvmax = NKV;
    if constexpr (CAUSAL) {
      kvmax = (row0w + WR - 1 - kv0) / 32 + 1;  // == jmax*16/32 (IQ==2)
      if (kvmax > NKV) kvmax = NKV;
    }
#pragma unroll
    for (int kk = 0; kk < NKV; kk++) {
      if (CAUSAL && kk >= kvmax) continue;
      short8 pa[IQ];
#pragma unroll
      for (int i = 0; i < IQ; i++)
        pa[i] = *(const short8*)&Ps[(wid * WR + i * 16 + fr) * VST + kk * 32 + grp * 8];
#pragma unroll
      for (int jd = 0; jd < 4; jd++) {
        short8 vb = *(const short8*)&Vs[(jd * 16 + fr) * VST + kk * 32 + grp * 8];
#pragma unroll
        for (int i = 0; i < IQ; i++)
          acc_o[i][jd] = __builtin_amdgcn_mfma_f32_16x16x32_bf16(pa[i], vb, acc_o[i][jd], 0, 0, 0);
      }
    }
  }

  // ---- finalize: O / l ----
#pragma unroll
  for (int i = 0; i < IQ; i++) {
#pragma unroll
    for (int r = 0; r < 4; r++) {
      float inv = 1.0f / l_run[i][r];
      long tok = (long)b * Tc + row0w + i * 16 + grp * 4 + r;
#pragma unroll
      for (int jd = 0; jd < 4; jd++)
        O[tok * 512 + h * 64 + jd * 16 + fr] = bfc(acc_o[i][jd][r] * inv);
    }
  }
}

// ---------------- host launcher ----------------
extern "C" void kernel_launch(void* const* d_in, const int* in_sizes, int n_in,
                              void* d_out, int out_size, void* d_ws, size_t ws_size,
                              hipStream_t stream) {
  const float* memory   = (const float*)d_in[0];
  const int*   mem_lens = (const int*)d_in[1];
  const int*   ys       = (const int*)d_in[2];
  const int*   ys_lens  = (const int*)d_in[3];
  const float* emb      = (const float*)d_in[4];
  const float* w_out    = (const float*)d_in[5];
  const float* b_out    = (const float*)d_in[6];
  const float* pp[26];
  for (int i = 0; i < 26; i++) pp[i] = (const float*)d_in[7 + i];

  // ---- ws layout (~126.4 MB of the 256 MiB ws) ----
  constexpr long PLW = 4194304;  // bf16 elems of transposed weights per layer
  constexpr long OFF_SAQ = 0, OFF_SAK = 262144, OFF_SAV = 524288, OFF_SAO = 786432,
                 OFF_CAQ = 1048576, OFF_CAK = 1310720, OFF_CAV = 1572864,
                 OFF_CAO = 1835008, OFF_FF1 = 2097152, OFF_FF2 = 3145728,
                 OFF_WOUT = 6 * PLW;
  u16*   Wt   = (u16*)d_ws;                          // 25,427,968 u16
  float* X    = (float*)(Wt + 25427968);             // 2,097,152 f32
  u16*   TO   = (u16*)(X + 2097152);                 // 2,097,152 bf16
  u16*   QKV  = TO + 2097152;                        // 3 x 2,097,152 bf16
  u16*   memb = QKV + 3 * 2097152;                   // 8,388,608 bf16
  u16*   Kb   = memb + 8388608;                      // 8,388,608 bf16 (cross K)
  u16*   SCR  = Kb + 8388608;                        // 8,388,608 bf16 (CA V / FF hidden)
  float* OUT  = (float*)d_out;

  auto WT = [&](const float* src, long dstoff, int K, int N, int Npad, int Lz,
                long srcStride, long dstStride) {
    dim3 g(Npad / 32, K / 32, Lz);
    wtrans_k<<<g, 256, 0, stream>>>(src, Wt + dstoff, K, N, srcStride, dstStride);
  };
  WT(pp[2],  OFF_SAQ, 512, 512, 512, Lc, 262144, PLW);
  WT(pp[4],  OFF_SAK, 512, 512, 512, Lc, 262144, PLW);
  WT(pp[6],  OFF_SAV, 512, 512, 512, Lc, 262144, PLW);
  WT(pp[8],  OFF_SAO, 512, 512, 512, Lc, 262144, PLW);
  WT(pp[12], OFF_CAQ, 512, 512, 512, Lc, 262144, PLW);
  WT(pp[14], OFF_CAK, 512, 512, 512, Lc, 262144, PLW);
  WT(pp[16], OFF_CAV, 512, 512, 512, Lc, 262144, PLW);
  WT(pp[18], OFF_CAO, 512, 512, 512, Lc, 262144, PLW);
  WT(pp[22], OFF_FF1, 512, 2048, 2048, Lc, 1048576, PLW);
  WT(pp[24], OFF_FF2, 2048, 512, 512, Lc, 1048576, PLW);
  WT(w_out,  OFF_WOUT, 512, 500, 512, 1, 0, 0);

  f2b_k<<<(NMEM * Dc / 4 + 255) / 256, 256, 0, stream>>>(memory, memb, (long)NMEM * Dc);
  embed_pe_k<<<NTOK, 256, 0, stream>>>(ys, emb, X);

  for (int l = 0; l < Lc; l++) {
    const u16* WtL = Wt + (long)l * PLW;

    // ======== self-attention ========
    layernorm_k<<<NTOK, 256, 0, stream>>>(X, pp[0] + (long)l * Dc, pp[1] + (long)l * Dc, TO);
    mgemm_k<4, 0, true, false, false, false><<<dim3(4, 32, 3), 256, 0, stream>>>(
        TO, WtL + OFF_SAQ, pp[3] + (long)l * Ac, pp[5] + (long)l * Ac, pp[7] + (long)l * Ac,
        QKV, nullptr, 512, 512, 512, 512, 512, 3, 0, 0, 0, 262144, 0, 2097152);
    fattn_k<128, 128, true, 2><<<dim3(256, 1), 256, 0, stream>>>(
        QKV, QKV + 2097152, QKV + 2 * 2097152, TO, ys_lens);
    mgemm_k<2, 1, true, true, false, false><<<dim3(4, 64, 1), 256, 0, stream>>>(
        TO, WtL + OFF_SAO, pp[9] + (long)l * Dc, nullptr, nullptr, X, X,
        512, 512, 512, 512, 512, 1, 0, 0, 0, 0, 0, 0);

    // ======== cross-attention ========
    layernorm_k<<<NTOK, 256, 0, stream>>>(X, pp[10] + (long)l * Dc, pp[11] + (long)l * Dc, TO);
    mgemm_k<2, 0, true, false, false, false><<<dim3(4, 64, 1), 256, 0, stream>>>(
        TO, WtL + OFF_CAQ, pp[13] + (long)l * Ac, nullptr, nullptr, QKV, nullptr,
        512, 512, 512, 512, 512, 1, 0, 0, 0, 0, 0, 0);
    // K -> Kb (bi=0), V -> SCR (bi=1); Kb and SCR contiguous (batCi = 8388608)
    mgemm_k<4, 0, true, false, false, false><<<dim3(4, 128, 2), 256, 0, stream>>>(
        memb, WtL + OFF_CAK, pp[15] + (long)l * Ac, pp[17] + (long)l * Ac, nullptr,
        Kb, nullptr, 512, 512, 512, 512, 512, 2, 0, 0, 0, 262144, 0, 8388608);
    fattn_k<512, 64, false, 1><<<dim3(256, 2), 256, 0, stream>>>(
        QKV, Kb, SCR, TO, mem_lens);
    mgemm_k<2, 1, true, true, false, false><<<dim3(4, 64, 1), 256, 0, stream>>>(
        TO, WtL + OFF_CAO, pp[19] + (long)l * Dc, nullptr, nullptr, X, X,
        512, 512, 512, 512, 512, 1, 0, 0, 0, 0, 0, 0);

    // ======== feed-forward ========
    layernorm_k<<<NTOK, 256, 0, stream>>>(X, pp[20] + (long)l * Dc, pp[21] + (long)l * Dc, TO);
    mgemm_k<4, 0, true, false, true, false><<<dim3(16, 32, 1), 256, 0, stream>>>(
        TO, WtL + OFF_FF1, pp[23] + (long)l * FFc, nullptr, nullptr, SCR, nullptr,
        2048, 512, 512, 512, 2048, 1, 0, 0, 0, 0, 0, 0);
    mgemm_k<2, 1, true, true, false, false><<<dim3(4, 64, 1), 256, 0, stream>>>(
        SCR, WtL + OFF_FF2, pp[25] + (long)l * Dc, nullptr, nullptr, X, X,
        512, 2048, 2048, 2048, 512, 1, 0, 0, 0, 0, 0, 0);
  }

  // final projection: X -> bf16 -> logits fp32 (N=500, ldc=500)
  f2b_k<<<(NTOK * Dc / 4 + 255) / 256, 256, 0, stream>>>(X, TO, (long)NTOK * Dc);
  mgemm_k<2, 1, true, false, false, true><<<dim3(4, 64, 1), 256, 0, stream>>>(
      TO, Wt + OFF_WOUT, b_out, nullptr, nullptr, OUT, nullptr,
      500, 512, 512, 512, 500, 1, 0, 0, 0, 0, 0, 0);
}

// Round 5
// 1224.663 us; speedup vs baseline: 4.6186x; 1.0225x over previous
//
#include <hip/hip_runtime.h>
#include <hip/hip_bf16.h>
#include <hip/hip_fp16.h>

// ---------------- problem constants ----------------
constexpr int Bc = 32, Sc = 512, Tc = 128, Dc = 512, Ac = 512, Hc = 8;
constexpr int HDc = 64, FFc = 2048, Lc = 6, Vc = 500;
constexpr int NTOK = Bc * Tc;   // 4096
constexpr int NMEM = Bc * Sc;   // 16384

typedef unsigned short u16;
typedef __attribute__((ext_vector_type(8))) short short8;  // 8 bf16 (4 VGPRs)
typedef __attribute__((ext_vector_type(4))) float f32x4;   // MFMA accumulator

__device__ __forceinline__ u16 bfc(float x) {
  __hip_bfloat16 h = __float2bfloat16(x);
  return *reinterpret_cast<u16*>(&h);
}

// async global->LDS, 16B per lane. LDS dest = wave-uniform base + lane*16.
__device__ __forceinline__ void gload16(const void* g, void* l) {
  __builtin_amdgcn_global_load_lds(
      (const __attribute__((address_space(1))) unsigned int*)g,
      (__attribute__((address_space(3))) unsigned int*)l, 16, 0, 0);
}

__device__ __forceinline__ float wave_sum(float v) {
#pragma unroll
  for (int o = 32; o > 0; o >>= 1) v += __shfl_down(v, o);
  return v;
}
__device__ __forceinline__ float wave_max(float v) {
#pragma unroll
  for (int o = 32; o > 0; o >>= 1) v = fmaxf(v, __shfl_down(v, o));
  return v;
}

// ---------------- embedding + sinusoidal PE (fp32 residual stream) ----------------
__global__ __launch_bounds__(256) void embed_pe_k(const int* __restrict__ ys,
                                                  const float* __restrict__ emb,
                                                  float* __restrict__ x) {
  int tok = blockIdx.x;
  int t = tok & (Tc - 1);
  int id = ys[tok];
  int j = threadIdx.x;
  int d0 = 2 * j;
  const float cdiv = -9.210340371976184f / (float)Dc;
  float div = expf((float)d0 * cdiv);
  float ang = (float)t * div;
  float pe0 = sinf(ang), pe1 = cosf(ang);
  const float sc = 22.627416997969522f;  // sqrt(512)
  long base = (long)tok * Dc + d0;
  long ebase = (long)id * Dc + d0;
  x[base]     = emb[ebase]     * sc + pe0;
  x[base + 1] = emb[ebase + 1] * sc + pe1;
}

// ---------------- layernorm fp32 -> bf16 ----------------
__global__ __launch_bounds__(256) void layernorm_k(const float* __restrict__ x,
                                                   const float* __restrict__ g,
                                                   const float* __restrict__ bta,
                                                   u16* __restrict__ out) {
  int row = blockIdx.x;
  int tid = threadIdx.x;
  const float* xr = x + (long)row * Dc;
  float2 xv = *(const float2*)(xr + tid * 2);
  __shared__ float red[4];
  float s = wave_sum(xv.x + xv.y);
  if ((tid & 63) == 0) red[tid >> 6] = s;
  __syncthreads();
  float mean = (red[0] + red[1] + red[2] + red[3]) * (1.0f / Dc);
  float dx0 = xv.x - mean, dx1 = xv.y - mean;
  __syncthreads();
  float s2 = wave_sum(dx0 * dx0 + dx1 * dx1);
  if ((tid & 63) == 0) red[tid >> 6] = s2;
  __syncthreads();
  float var = (red[0] + red[1] + red[2] + red[3]) * (1.0f / Dc);
  float rstd = rsqrtf(var + 1e-5f);
  ushort2 o;
  o.x = bfc(dx0 * rstd * g[2 * tid] + bta[2 * tid]);
  o.y = bfc(dx1 * rstd * g[2 * tid + 1] + bta[2 * tid + 1]);
  *(ushort2*)(out + (long)row * Dc + tid * 2) = o;
}

// ---------------- weight transpose+convert: W(K x N) fp32 -> Wt(Npad x K) bf16 ----------------
__global__ __launch_bounds__(256) void wtrans_k(const float* __restrict__ src,
                                                u16* __restrict__ dst,
                                                int K, int N, long srcStride, long dstStride) {
  int z = blockIdx.z;
  src += z * srcStride;
  dst += z * dstStride;
  __shared__ float t[32][33];
  int n0 = blockIdx.x * 32, k0 = blockIdx.y * 32;
  int tx = threadIdx.x & 31, ty = threadIdx.x >> 5;  // 32 x 8
#pragma unroll
  for (int i = 0; i < 4; i++) {
    int n = n0 + tx;
    t[ty + 8 * i][tx] = (n < N) ? src[(long)(k0 + ty + 8 * i) * N + n] : 0.0f;
  }
  __syncthreads();
#pragma unroll
  for (int i = 0; i < 4; i++) {
    dst[(long)(n0 + ty + 8 * i) * K + k0 + tx] = bfc(t[tx][ty + 8 * i]);
  }
}

// ---------------- batched 512x512 weight transpose: 8 weight sets x 6 layers ----------------
struct PtrPack8 { const float* p[8]; };
__global__ __launch_bounds__(256) void wtrans8_k(PtrPack8 P, u16* __restrict__ Wt,
                                                 long PLW) {
  int z = blockIdx.z;            // widx*6 + l
  int widx = z / 6, l = z - widx * 6;
  const float* src = P.p[widx] + (long)l * 262144;
  u16* dst = Wt + (long)widx * 262144 + (long)l * PLW;
  __shared__ float t[32][33];
  int n0 = blockIdx.x * 32, k0 = blockIdx.y * 32;
  int tx = threadIdx.x & 31, ty = threadIdx.x >> 5;
#pragma unroll
  for (int i = 0; i < 4; i++)
    t[ty + 8 * i][tx] = src[(long)(k0 + ty + 8 * i) * 512 + n0 + tx];
  __syncthreads();
#pragma unroll
  for (int i = 0; i < 4; i++)
    dst[(long)(n0 + ty + 8 * i) * 512 + k0 + tx] = bfc(t[tx][ty + 8 * i]);
}

// ---------------- fp32 -> bf16 convert ----------------
__global__ __launch_bounds__(256) void f2b_k(const float* __restrict__ in,
                                             u16* __restrict__ out, long n) {
  long i = ((long)blockIdx.x * 256 + threadIdx.x) * 4;
  if (i >= n) return;
  float4 v = *(const float4*)(in + i);
  ushort4 o;
  o.x = bfc(v.x); o.y = bfc(v.y); o.z = bfc(v.z); o.w = bfc(v.w);
  *(ushort4*)(out + i) = o;
}

// ---------------- bf16 MFMA GEMM, 2-phase prefetch, T1 XCD swizzle, BM = BMW*32, BN = 128 ----
// C = act(A(MxK,bf16) @ Bt(NxK,bf16)^T + bias [+ R])
// 256 threads = 4 waves in 2x2. Double-buffered LDS; stage(next) issued BEFORE
// compute(current); ONE __syncthreads per K-step.
// MLEN: skip m-blocks whose rows (mod 512) are all >= mlens[row/512] (CA K/V proj:
// masked-out memory rows; consumers mask those score columns so stale data is harmless).
// OMODE: 0 = bf16 out, 1 = fp32 out.
template <int BMW, int OMODE, bool BIAS, bool RES, bool SWISH, bool NCH, bool MLEN>
__global__ __launch_bounds__(256) void mgemm_k(
    const u16* __restrict__ A, const u16* __restrict__ Bt,
    const float* __restrict__ bias0, const float* __restrict__ bias1,
    const float* __restrict__ bias2,
    void* __restrict__ Cv, const float* __restrict__ R, const int* __restrict__ mlens,
    int N, int K, int lda, int ldb, int ldc, int nbi,
    long batAo, long batAi, long batBo, long batBi, long batCo, long batCi) {
  constexpr int BM = BMW * 32;

  // T1: bijective XCD-aware swizzle (m204) over the flattened grid.
  int gx = gridDim.x, gy = gridDim.y;
  int nwg = gx * gy * gridDim.z;
  int orig = blockIdx.x + gx * (blockIdx.y + gy * blockIdx.z);
  int q = nwg >> 3, r = nwg & 7, xcd = orig & 7, off = orig >> 3;
  int wgid = (xcd < r ? xcd * (q + 1) : r * (q + 1) + (xcd - r) * q) + off;
  int bxi = wgid % gx; int tmp = wgid / gx;
  int byi = tmp % gy;  int bzi = tmp / gy;

  int z = bzi;
  int bo = z / nbi, bi = z - bo * nbi;
  int m0 = byi * BM, n0 = bxi * 128;

  if constexpr (MLEN) {
    if ((m0 & 511) >= mlens[m0 >> 9]) return;  // whole block beyond memory len
  }

  const u16* Ab = A + bo * batAo + bi * batAi;
  const u16* Bb = Bt + bo * batBo + bi * batBi;
  long coff = bo * batCo + bi * batCi;
  const float* bias = nullptr;
  if constexpr (BIAS) bias = (bi == 0) ? bias0 : ((bi == 1) ? bias1 : bias2);

  __shared__ __align__(16) u16 As[2][BM * 32];
  __shared__ __align__(16) u16 Bs[2][128 * 32];

  int tid = threadIdx.x;
  int lane = tid & 63, wid = tid >> 6;
  int wm = wid >> 1, wn = wid & 1;
  int fr = lane & 15, grp = lane >> 4;

  f32x4 acc[BMW][4];
#pragma unroll
  for (int i = 0; i < BMW; i++)
#pragma unroll
    for (int j = 0; j < 4; j++) acc[i][j] = (f32x4){0.f, 0.f, 0.f, 0.f};

  const u16* ga = Ab + (long)(m0 + (tid >> 2)) * lda + ((tid & 3) << 3);
  const u16* gb = Bb + (long)(n0 + (tid >> 2)) * ldb + ((tid & 3) << 3);

  auto STAGE = [&](int buf, int kt) {
    u16* lA = &As[buf][tid * 8];
    u16* lB = &Bs[buf][tid * 8];
    gload16(ga + kt, lA);
    if constexpr (BM == 128) gload16(ga + kt + (long)64 * lda, lA + 2048);
    gload16(gb + kt, lB);
    gload16(gb + kt + (long)64 * ldb, lB + 2048);
  };

  auto COMPUTE = [&](int buf) {
    short8 av[BMW], bv[4];
#pragma unroll
    for (int i = 0; i < BMW; i++)
      av[i] = *(const short8*)&As[buf][(wm * BMW * 16 + i * 16 + fr) * 32 + grp * 8];
#pragma unroll
    for (int j = 0; j < 4; j++)
      bv[j] = *(const short8*)&Bs[buf][(wn * 64 + j * 16 + fr) * 32 + grp * 8];
#pragma unroll
    for (int i = 0; i < BMW; i++)
#pragma unroll
      for (int j = 0; j < 4; j++)
        acc[i][j] = __builtin_amdgcn_mfma_f32_16x16x32_bf16(av[i], bv[j], acc[i][j], 0, 0, 0);
  };

  STAGE(0, 0);
  __syncthreads();          // vmcnt(0) drain + barrier: tile 0 resident
  int cur = 0;
  for (int kt = 32; kt < K; kt += 32) {
    STAGE(cur ^ 1, kt);     // issue next-tile loads first: latency hides under MFMA
    COMPUTE(cur);
    __syncthreads();        // staged writes landed + all reads of 'cur' retired
    cur ^= 1;
  }
  COMPUTE(cur);             // last tile, no prefetch

  int rbase = m0 + wm * BMW * 16 + grp * 4;
  int cbase = n0 + wn * 64 + fr;
#pragma unroll
  for (int i = 0; i < BMW; i++) {
#pragma unroll
    for (int j = 0; j < 4; j++) {
      int col = cbase + j * 16;
      if (NCH && col >= N) continue;
      float bb = 0.0f;
      if constexpr (BIAS) bb = bias[col];
#pragma unroll
      for (int r2 = 0; r2 < 4; r2++) {
        int row = rbase + i * 16 + r2;
        float v = acc[i][j][r2] + bb;
        long idx = coff + (long)row * ldc + col;
        if constexpr (RES) v += R[idx];
        if constexpr (SWISH) v = v / (1.0f + expf(-v));
        if constexpr (OMODE == 0) ((u16*)Cv)[idx] = bfc(v);
        else ((float*)Cv)[idx] = v;
      }
    }
  }
}

// ---------------- fused flash attention ----------------
// Grid (b*H, qb). 256 thr = 4 waves; each wave owns WR=16*IQ q rows.
// Q/K/V all token-major [.,512] bf16 (col = h*64+d); V transposed into LDS at staging.
// O: [token][512]. CAUSAL requires IQ==2 (jmax*16 == kvmax*32 alignment).
template <int SKV, int KVBLK, bool CAUSAL, int IQ>
__global__ __launch_bounds__(256) void fattn_k(
    const u16* __restrict__ Q, const u16* __restrict__ Kg, const u16* __restrict__ Vg,
    u16* __restrict__ O, const int* __restrict__ lens) {
  constexpr int NJ  = KVBLK / 16;   // S col fragments per tile
  constexpr int NKV = KVBLK / 32;   // PV k-steps per tile
  constexpr int NT  = SKV / KVBLK;  // tiles
  constexpr int KST = 72;           // K lds row stride (u16), padded
  constexpr int VST = KVBLK + 8;    // Vt / P lds row stride (u16), padded
  constexpr int WR  = 16 * IQ;      // q rows per wave
  constexpr int WGR = 64 * IQ;      // q rows per workgroup
  constexpr int CH  = KVBLK / 32;   // 16B chunks per thread for K tile (= V tile)

  __shared__ __align__(16) u16 Ks[KVBLK * KST];
  __shared__ __align__(16) u16 Vs[64 * VST];
  __shared__ __align__(16) u16 Ps[WGR * VST];

  int bh = blockIdx.x; int b = bh >> 3, h = bh & 7;
  int row00 = blockIdx.y * WGR;
  int tid = threadIdx.x, lane = tid & 63, wid = tid >> 6;
  int fr = lane & 15, grp = lane >> 4;
  int len = lens[b];
  int row0w = row00 + wid * WR;

  // Q fragments: row = row0w + i*16 + fr, elems d = k2*32 + grp*8
  short8 qa[IQ][2];
  {
    const u16* qp = Q + ((long)b * Tc + row0w + fr) * 512 + h * 64 + grp * 8;
#pragma unroll
    for (int i = 0; i < IQ; i++)
#pragma unroll
      for (int k2 = 0; k2 < 2; k2++)
        qa[i][k2] = *(const short8*)(qp + (long)i * 16 * 512 + k2 * 32);
  }

  float m_run[IQ][4], l_run[IQ][4];
  f32x4 acc_o[IQ][4];
#pragma unroll
  for (int i = 0; i < IQ; i++)
#pragma unroll
    for (int r = 0; r < 4; r++) { m_run[i][r] = -1e30f; l_run[i][r] = 0.0f; }
#pragma unroll
  for (int i = 0; i < IQ; i++)
#pragma unroll
    for (int j = 0; j < 4; j++) acc_o[i][j] = (f32x4){0.f, 0.f, 0.f, 0.f};

  const u16* Kbase = Kg + ((long)b * SKV) * 512 + h * 64;
  const u16* Vbase = Vg + ((long)b * SKV) * 512 + h * 64;

  // tile count: causal bound (wg-uniform) and len bound (wg-uniform)
  int NTeff = NT;
  if constexpr (CAUSAL) NTeff = (row00 + WGR - 1) / KVBLK + 1;
  int lenT = (len + KVBLK - 1) / KVBLK;   // tiles wholly beyond len contribute 0
  if (lenT < NTeff) NTeff = lenT;

  short8 kreg[CH], vreg[CH];
  // preload tile 0 (K rows coalesced; V rows coalesced, transposed at LDS write)
#pragma unroll
  for (int c = 0; c < CH; c++) {
    int idx = tid + 256 * c; int kv = idx >> 3, s = idx & 7;
    kreg[c] = *(const short8*)(Kbase + (long)kv * 512 + s * 8);
    vreg[c] = *(const short8*)(Vbase + (long)kv * 512 + s * 8);
  }

  for (int t = 0; t < NTeff; t++) {
    int kv0 = t * KVBLK;
    __syncthreads();  // prior-tile LDS reads done (all waves)
#pragma unroll
    for (int c = 0; c < CH; c++) {
      int idx = tid + 256 * c; int kv = idx >> 3, s = idx & 7;
      *(short8*)&Ks[kv * KST + s * 8] = kreg[c];
#pragma unroll
      for (int j = 0; j < 8; j++)
        Vs[(s * 8 + j) * VST + kv] = (u16)vreg[c][j];   // transpose: Vs[d][kv]
    }
    __syncthreads();  // LDS ready
    // prefetch next tile into regs (overlaps with compute below)
    if (t + 1 < NTeff) {
      int kvn = kv0 + KVBLK;
#pragma unroll
      for (int c = 0; c < CH; c++) {
        int idx = tid + 256 * c; int kv = idx >> 3, s = idx & 7;
        kreg[c] = *(const short8*)(Kbase + (long)(kvn + kv) * 512 + s * 8);
        vreg[c] = *(const short8*)(Vbase + (long)(kvn + kv) * 512 + s * 8);
      }
    }

    int jmax = NJ;
    if constexpr (CAUSAL) {
      jmax = (row0w + WR - 1 - kv0) / 16 + 1;  // wave-uniform
      if (jmax > NJ) jmax = NJ;
    }

    // ---- S = Q @ K^T ----
    f32x4 accs[IQ][NJ];
    __builtin_amdgcn_s_setprio(1);
#pragma unroll
    for (int j = 0; j < NJ; j++) {
      if (CAUSAL && j >= jmax) continue;
      short8 bv0 = *(const short8*)&Ks[(j * 16 + fr) * KST + grp * 8];
      short8 bv1 = *(const short8*)&Ks[(j * 16 + fr) * KST + 32 + grp * 8];
#pragma unroll
      for (int i = 0; i < IQ; i++) {
        f32x4 a = __builtin_amdgcn_mfma_f32_16x16x32_bf16(qa[i][0], bv0, (f32x4){0.f,0.f,0.f,0.f}, 0, 0, 0);
        accs[i][j] = __builtin_amdgcn_mfma_f32_16x16x32_bf16(qa[i][1], bv1, a, 0, 0, 0);
      }
    }
    __builtin_amdgcn_s_setprio(0);

    // ---- online softmax ----
    float alpha[IQ][4];
#pragma unroll
    for (int i = 0; i < IQ; i++) {
#pragma unroll
      for (int r = 0; r < 4; r++) {
        int qrow = row0w + i * 16 + grp * 4 + r;
        float vmax = -1e30f;
#pragma unroll
        for (int j = 0; j < NJ; j++) {
          if (CAUSAL && j >= jmax) continue;
          int kvb = kv0 + j * 16 + fr;
          float s = accs[i][j][r] * 0.125f;
          bool msk = (kvb >= len) || (CAUSAL && kvb > qrow);
          s = msk ? -1e30f : s;
          accs[i][j][r] = s;
          vmax = fmaxf(vmax, s);
        }
        vmax = fmaxf(vmax, __shfl_xor(vmax, 1));
        vmax = fmaxf(vmax, __shfl_xor(vmax, 2));
        vmax = fmaxf(vmax, __shfl_xor(vmax, 4));
        vmax = fmaxf(vmax, __shfl_xor(vmax, 8));
        float mn = fmaxf(m_run[i][r], vmax);
        float al = __expf(m_run[i][r] - mn);
        m_run[i][r] = mn;
        alpha[i][r] = al;
        float rs = 0.0f;
#pragma unroll
        for (int j = 0; j < NJ; j++) {
          if (CAUSAL && j >= jmax) continue;
          float p = __expf(accs[i][j][r] - mn);
          accs[i][j][r] = p;
          rs += p;
        }
        rs += __shfl_xor(rs, 1);
        rs += __shfl_xor(rs, 2);
        rs += __shfl_xor(rs, 4);
        rs += __shfl_xor(rs, 8);
        l_run[i][r] = l_run[i][r] * al + rs;
      }
    }

    // ---- write P (bf16) to per-wave LDS region ----
#pragma unroll
    for (int i = 0; i < IQ; i++)
#pragma unroll
      for (int j = 0; j < NJ; j++) {
        if (CAUSAL && j >= jmax) continue;
#pragma unroll
        for (int r = 0; r < 4; r++) {
          int prow = wid * WR + i * 16 + grp * 4 + r;
          Ps[prow * VST + j * 16 + fr] = bfc(accs[i][j][r]);
        }
      }

    // ---- rescale O ----
#pragma unroll
    for (int i = 0; i < IQ; i++)
#pragma unroll
      for (int jd = 0; jd < 4; jd++)
#pragma unroll
        for (int r = 0; r < 4; r++)
          acc_o[i][jd][r] *= alpha[i][r];

    // ---- O += P @ V ----
    int kvmax = NKV;
    if constexpr (CAUSAL) {
      kvmax = (row0w + WR - 1 - kv0) / 32 + 1;  // == jmax*16/32 (IQ==2)
      if (kvmax > NKV) kvmax = NKV;
    }
    __builtin_amdgcn_s_setprio(1);
#pragma unroll
    for (int kk = 0; kk < NKV; kk++) {
      if (CAUSAL && kk >= kvmax) continue;
      short8 pa[IQ];
#pragma unroll
      for (int i = 0; i < IQ; i++)
        pa[i] = *(const short8*)&Ps[(wid * WR + i * 16 + fr) * VST + kk * 32 + grp * 8];
#pragma unroll
      for (int jd = 0; jd < 4; jd++) {
        short8 vb = *(const short8*)&Vs[(jd * 16 + fr) * VST + kk * 32 + grp * 8];
#pragma unroll
        for (int i = 0; i < IQ; i++)
          acc_o[i][jd] = __builtin_amdgcn_mfma_f32_16x16x32_bf16(pa[i], vb, acc_o[i][jd], 0, 0, 0);
      }
    }
    __builtin_amdgcn_s_setprio(0);
  }

  // ---- finalize: O / l ----
#pragma unroll
  for (int i = 0; i < IQ; i++) {
#pragma unroll
    for (int r = 0; r < 4; r++) {
      float inv = 1.0f / l_run[i][r];
      long tok = (long)b * Tc + row0w + i * 16 + grp * 4 + r;
#pragma unroll
      for (int jd = 0; jd < 4; jd++)
        O[tok * 512 + h * 64 + jd * 16 + fr] = bfc(acc_o[i][jd][r] * inv);
    }
  }
}

// ---------------- host launcher ----------------
extern "C" void kernel_launch(void* const* d_in, const int* in_sizes, int n_in,
                              void* d_out, int out_size, void* d_ws, size_t ws_size,
                              hipStream_t stream) {
  const float* memory   = (const float*)d_in[0];
  const int*   mem_lens = (const int*)d_in[1];
  const int*   ys       = (const int*)d_in[2];
  const int*   ys_lens  = (const int*)d_in[3];
  const float* emb      = (const float*)d_in[4];
  const float* w_out    = (const float*)d_in[5];
  const float* b_out    = (const float*)d_in[6];
  const float* pp[26];
  for (int i = 0; i < 26; i++) pp[i] = (const float*)d_in[7 + i];

  // ---- ws layout (~126.4 MB of the 256 MiB ws) ----
  constexpr long PLW = 4194304;  // bf16 elems of transposed weights per layer
  constexpr long OFF_SAQ = 0, OFF_SAK = 262144, OFF_SAV = 524288, OFF_SAO = 786432,
                 OFF_CAQ = 1048576, OFF_CAK = 1310720, OFF_CAV = 1572864,
                 OFF_CAO = 1835008, OFF_FF1 = 2097152, OFF_FF2 = 3145728,
                 OFF_WOUT = 6 * PLW;
  u16*   Wt   = (u16*)d_ws;                          // 25,427,968 u16
  float* X    = (float*)(Wt + 25427968);             // 2,097,152 f32
  u16*   TO   = (u16*)(X + 2097152);                 // 2,097,152 bf16
  u16*   QKV  = TO + 2097152;                        // 3 x 2,097,152 bf16
  u16*   memb = QKV + 3 * 2097152;                   // 8,388,608 bf16
  u16*   Kb   = memb + 8388608;                      // 8,388,608 bf16 (cross K)
  u16*   SCR  = Kb + 8388608;                        // 8,388,608 bf16 (CA V / FF hidden)
  float* OUT  = (float*)d_out;

  // 8 square (512x512) weight families in one dispatch (z = widx*6 + l)
  PtrPack8 P8;
  P8.p[0] = pp[2];  P8.p[1] = pp[4];  P8.p[2] = pp[6];  P8.p[3] = pp[8];
  P8.p[4] = pp[12]; P8.p[5] = pp[14]; P8.p[6] = pp[16]; P8.p[7] = pp[18];
  wtrans8_k<<<dim3(16, 16, 48), 256, 0, stream>>>(P8, Wt, PLW);
  wtrans_k<<<dim3(64, 16, Lc), 256, 0, stream>>>(pp[22], Wt + OFF_FF1, 512, 2048, 1048576, PLW);
  wtrans_k<<<dim3(16, 64, Lc), 256, 0, stream>>>(pp[24], Wt + OFF_FF2, 2048, 512, 1048576, PLW);
  wtrans_k<<<dim3(16, 16, 1), 256, 0, stream>>>(w_out, Wt + OFF_WOUT, 512, 500, 0, 0);

  f2b_k<<<(NMEM * Dc / 4 + 255) / 256, 256, 0, stream>>>(memory, memb, (long)NMEM * Dc);
  embed_pe_k<<<NTOK, 256, 0, stream>>>(ys, emb, X);

  for (int l = 0; l < Lc; l++) {
    const u16* WtL = Wt + (long)l * PLW;

    // ======== self-attention ========
    layernorm_k<<<NTOK, 256, 0, stream>>>(X, pp[0] + (long)l * Dc, pp[1] + (long)l * Dc, TO);
    mgemm_k<4, 0, true, false, false, false, false><<<dim3(4, 32, 3), 256, 0, stream>>>(
        TO, WtL + OFF_SAQ, pp[3] + (long)l * Ac, pp[5] + (long)l * Ac, pp[7] + (long)l * Ac,
        QKV, nullptr, nullptr, 512, 512, 512, 512, 512, 3, 0, 0, 0, 262144, 0, 2097152);
    fattn_k<128, 128, true, 2><<<dim3(256, 1), 256, 0, stream>>>(
        QKV, QKV + 2097152, QKV + 2 * 2097152, TO, ys_lens);
    mgemm_k<2, 1, true, true, false, false, false><<<dim3(4, 64, 1), 256, 0, stream>>>(
        TO, WtL + OFF_SAO, pp[9] + (long)l * Dc, nullptr, nullptr, X, X, nullptr,
        512, 512, 512, 512, 512, 1, 0, 0, 0, 0, 0, 0);

    // ======== cross-attention ========
    layernorm_k<<<NTOK, 256, 0, stream>>>(X, pp[10] + (long)l * Dc, pp[11] + (long)l * Dc, TO);
    mgemm_k<2, 0, true, false, false, false, false><<<dim3(4, 64, 1), 256, 0, stream>>>(
        TO, WtL + OFF_CAQ, pp[13] + (long)l * Ac, nullptr, nullptr, QKV, nullptr, nullptr,
        512, 512, 512, 512, 512, 1, 0, 0, 0, 0, 0, 0);
    // K -> Kb (bi=0), V -> SCR (bi=1); blocks fully beyond mem_lens skipped (MLEN)
    mgemm_k<4, 0, true, false, false, false, true><<<dim3(4, 128, 2), 256, 0, stream>>>(
        memb, WtL + OFF_CAK, pp[15] + (long)l * Ac, pp[17] + (long)l * Ac, nullptr,
        Kb, nullptr, mem_lens, 512, 512, 512, 512, 512, 2, 0, 0, 0, 262144, 0, 8388608);
    fattn_k<512, 128, false, 1><<<dim3(256, 2), 256, 0, stream>>>(
        QKV, Kb, SCR, TO, mem_lens);
    mgemm_k<2, 1, true, true, false, false, false><<<dim3(4, 64, 1), 256, 0, stream>>>(
        TO, WtL + OFF_CAO, pp[19] + (long)l * Dc, nullptr, nullptr, X, X, nullptr,
        512, 512, 512, 512, 512, 1, 0, 0, 0, 0, 0, 0);

    // ======== feed-forward ========
    layernorm_k<<<NTOK, 256, 0, stream>>>(X, pp[20] + (long)l * Dc, pp[21] + (long)l * Dc, TO);
    mgemm_k<4, 0, true, false, true, false, false><<<dim3(16, 32, 1), 256, 0, stream>>>(
        TO, WtL + OFF_FF1, pp[23] + (long)l * FFc, nullptr, nullptr, SCR, nullptr, nullptr,
        2048, 512, 512, 512, 2048, 1, 0, 0, 0, 0, 0, 0);
    mgemm_k<2, 1, true, true, false, false, false><<<dim3(4, 64, 1), 256, 0, stream>>>(
        SCR, WtL + OFF_FF2, pp[25] + (long)l * Dc, nullptr, nullptr, X, X, nullptr,
        512, 2048, 2048, 2048, 512, 1, 0, 0, 0, 0, 0, 0);
  }

  // final projection: X -> bf16 -> logits fp32 (N=500, ldc=500)
  f2b_k<<<(NTOK * Dc / 4 + 255) / 256, 256, 0, stream>>>(X, TO, (long)NTOK * Dc);
  mgemm_k<2, 1, true, false, false, true, false><<<dim3(4, 64, 1), 256, 0, stream>>>(
      TO, Wt + OFF_WOUT, b_out, nullptr, nullptr, OUT, nullptr, nullptr,
      500, 512, 512, 512, 500, 1, 0, 0, 0, 0, 0, 0);
}

// Round 6
// 1184.944 us; speedup vs baseline: 4.7734x; 1.0335x over previous
//
#include <hip/hip_runtime.h>
#include <hip/hip_bf16.h>
#include <hip/hip_fp16.h>

// ---------------- problem constants ----------------
constexpr int Bc = 32, Sc = 512, Tc = 128, Dc = 512, Ac = 512, Hc = 8;
constexpr int HDc = 64, FFc = 2048, Lc = 6, Vc = 500;
constexpr int NTOK = Bc * Tc;   // 4096
constexpr int NMEM = Bc * Sc;   // 16384

typedef unsigned short u16;
typedef __attribute__((ext_vector_type(8))) short short8;  // 8 bf16 (4 VGPRs)
typedef __attribute__((ext_vector_type(4))) float f32x4;   // MFMA accumulator

__device__ __forceinline__ u16 bfc(float x) {
  __hip_bfloat16 h = __float2bfloat16(x);
  return *reinterpret_cast<u16*>(&h);
}

// async global->LDS, 16B per lane. LDS dest = wave-uniform base + lane*16.
__device__ __forceinline__ void gload16(const void* g, void* l) {
  __builtin_amdgcn_global_load_lds(
      (const __attribute__((address_space(1))) unsigned int*)g,
      (__attribute__((address_space(3))) unsigned int*)l, 16, 0, 0);
}

// counted vmcnt wait + scheduler fence (rule #18: sched_barrier after inline waitcnt)
template <int N>
__device__ __forceinline__ void waitv() {
  if constexpr (N == 8)      asm volatile("s_waitcnt vmcnt(8)" ::: "memory");
  else if constexpr (N == 6) asm volatile("s_waitcnt vmcnt(6)" ::: "memory");
  else if constexpr (N == 4) asm volatile("s_waitcnt vmcnt(4)" ::: "memory");
  else if constexpr (N == 3) asm volatile("s_waitcnt vmcnt(3)" ::: "memory");
  else                       asm volatile("s_waitcnt vmcnt(0)" ::: "memory");
  __builtin_amdgcn_sched_barrier(0);
}
__device__ __forceinline__ void barrier_fenced() {
  __builtin_amdgcn_s_barrier();
  __builtin_amdgcn_sched_barrier(0);
}
__device__ __forceinline__ void lgk0_barrier() {
  asm volatile("s_waitcnt lgkmcnt(0)" ::: "memory");
  __builtin_amdgcn_sched_barrier(0);
  __builtin_amdgcn_s_barrier();
  __builtin_amdgcn_sched_barrier(0);
}

__device__ __forceinline__ float wave_sum(float v) {
#pragma unroll
  for (int o = 32; o > 0; o >>= 1) v += __shfl_down(v, o);
  return v;
}
__device__ __forceinline__ float wave_max(float v) {
#pragma unroll
  for (int o = 32; o > 0; o >>= 1) v = fmaxf(v, __shfl_down(v, o));
  return v;
}

// ---------------- embedding + sinusoidal PE (fp32 residual stream) ----------------
__global__ __launch_bounds__(256) void embed_pe_k(const int* __restrict__ ys,
                                                  const float* __restrict__ emb,
                                                  float* __restrict__ x) {
  int tok = blockIdx.x;
  int t = tok & (Tc - 1);
  int id = ys[tok];
  int j = threadIdx.x;
  int d0 = 2 * j;
  const float cdiv = -9.210340371976184f / (float)Dc;
  float div = expf((float)d0 * cdiv);
  float ang = (float)t * div;
  float pe0 = sinf(ang), pe1 = cosf(ang);
  const float sc = 22.627416997969522f;  // sqrt(512)
  long base = (long)tok * Dc + d0;
  long ebase = (long)id * Dc + d0;
  x[base]     = emb[ebase]     * sc + pe0;
  x[base + 1] = emb[ebase + 1] * sc + pe1;
}

// ---------------- layernorm fp32 -> bf16 (one-pass: sum + sumsq together) ----------------
__global__ __launch_bounds__(256) void layernorm_k(const float* __restrict__ x,
                                                   const float* __restrict__ g,
                                                   const float* __restrict__ bta,
                                                   u16* __restrict__ out) {
  int row = blockIdx.x;
  int tid = threadIdx.x;
  const float* xr = x + (long)row * Dc;
  float2 xv = *(const float2*)(xr + tid * 2);
  float s  = xv.x + xv.y;
  float s2 = xv.x * xv.x + xv.y * xv.y;
  __shared__ float red[4], red2[4];
#pragma unroll
  for (int o = 32; o > 0; o >>= 1) {
    s  += __shfl_down(s, o);
    s2 += __shfl_down(s2, o);
  }
  if ((tid & 63) == 0) { red[tid >> 6] = s; red2[tid >> 6] = s2; }
  __syncthreads();
  float mean = (red[0] + red[1] + red[2] + red[3]) * (1.0f / Dc);
  float ms   = (red2[0] + red2[1] + red2[2] + red2[3]) * (1.0f / Dc);
  float var  = ms - mean * mean;
  float rstd = rsqrtf(var + 1e-5f);
  float dx0 = xv.x - mean, dx1 = xv.y - mean;
  ushort2 o;
  o.x = bfc(dx0 * rstd * g[2 * tid] + bta[2 * tid]);
  o.y = bfc(dx1 * rstd * g[2 * tid + 1] + bta[2 * tid + 1]);
  *(ushort2*)(out + (long)row * Dc + tid * 2) = o;
}

// ---------------- weight transpose+convert: W(K x N) fp32 -> Wt(Npad x K) bf16 ----------------
__global__ __launch_bounds__(256) void wtrans_k(const float* __restrict__ src,
                                                u16* __restrict__ dst,
                                                int K, int N, long srcStride, long dstStride) {
  int z = blockIdx.z;
  src += z * srcStride;
  dst += z * dstStride;
  __shared__ float t[32][33];
  int n0 = blockIdx.x * 32, k0 = blockIdx.y * 32;
  int tx = threadIdx.x & 31, ty = threadIdx.x >> 5;  // 32 x 8
#pragma unroll
  for (int i = 0; i < 4; i++) {
    int n = n0 + tx;
    t[ty + 8 * i][tx] = (n < N) ? src[(long)(k0 + ty + 8 * i) * N + n] : 0.0f;
  }
  __syncthreads();
#pragma unroll
  for (int i = 0; i < 4; i++) {
    dst[(long)(n0 + ty + 8 * i) * K + k0 + tx] = bfc(t[tx][ty + 8 * i]);
  }
}

// ---------------- batched 512x512 weight transpose: 8 weight sets x 6 layers ----------------
struct PtrPack8 { const float* p[8]; };
__global__ __launch_bounds__(256) void wtrans8_k(PtrPack8 P, u16* __restrict__ Wt,
                                                 long PLW) {
  int z = blockIdx.z;            // widx*6 + l
  int widx = z / 6, l = z - widx * 6;
  const float* src = P.p[widx] + (long)l * 262144;
  u16* dst = Wt + (long)widx * 262144 + (long)l * PLW;
  __shared__ float t[32][33];
  int n0 = blockIdx.x * 32, k0 = blockIdx.y * 32;
  int tx = threadIdx.x & 31, ty = threadIdx.x >> 5;
#pragma unroll
  for (int i = 0; i < 4; i++)
    t[ty + 8 * i][tx] = src[(long)(k0 + ty + 8 * i) * 512 + n0 + tx];
  __syncthreads();
#pragma unroll
  for (int i = 0; i < 4; i++)
    dst[(long)(n0 + ty + 8 * i) * 512 + k0 + tx] = bfc(t[tx][ty + 8 * i]);
}

// ---------------- fp32 -> bf16 convert ----------------
__global__ __launch_bounds__(256) void f2b_k(const float* __restrict__ in,
                                             u16* __restrict__ out, long n) {
  long i = ((long)blockIdx.x * 256 + threadIdx.x) * 4;
  if (i >= n) return;
  float4 v = *(const float4*)(in + i);
  ushort4 o;
  o.x = bfc(v.x); o.y = bfc(v.y); o.z = bfc(v.z); o.w = bfc(v.w);
  *(ushort4*)(out + i) = o;
}

// ---------------- bf16 MFMA GEMM: 3-buffer ring, counted vmcnt (T3+T4), T1 swizzle -------
// C = act(A(MxK,bf16) @ Bt(NxK,bf16)^T + bias [+ R]); BM = BMW*32, BN = 128.
// 256 threads = 4 waves in 2x2. Pipeline: tiles t, t+1, t+2 in flight; per K-step
// wait vmcnt(2*LPS) (tile t's loads done, t+1/t+2 stay in flight) -> s_barrier ->
// MFMA -> lgkmcnt(0)+s_barrier (WAR protection for ring overwrite). Tail peeled.
// MLEN: skip m-blocks fully beyond mlens (CA K/V: consumers mask those columns).
// OMODE: 0 = bf16 out, 1 = fp32 out.
template <int BMW, int OMODE, bool BIAS, bool RES, bool SWISH, bool NCH, bool MLEN>
__global__ __launch_bounds__(256) void mgemm_k(
    const u16* __restrict__ A, const u16* __restrict__ Bt,
    const float* __restrict__ bias0, const float* __restrict__ bias1,
    const float* __restrict__ bias2,
    void* __restrict__ Cv, const float* __restrict__ R, const int* __restrict__ mlens,
    int N, int K, int lda, int ldb, int ldc, int nbi,
    long batAo, long batAi, long batBo, long batBi, long batCo, long batCi) {
  constexpr int BM = BMW * 32;
  constexpr int LPS = (BM == 128 ? 2 : 1) + 2;   // global_load_lds per STAGE per wave

  // T1: bijective XCD-aware swizzle (m204) over the flattened grid.
  int gx = gridDim.x, gy = gridDim.y;
  int nwg = gx * gy * gridDim.z;
  int orig = blockIdx.x + gx * (blockIdx.y + gy * blockIdx.z);
  int q = nwg >> 3, r = nwg & 7, xcd = orig & 7, off = orig >> 3;
  int wgid = (xcd < r ? xcd * (q + 1) : r * (q + 1) + (xcd - r) * q) + off;
  int bxi = wgid % gx; int tmp = wgid / gx;
  int byi = tmp % gy;  int bzi = tmp / gy;

  int z = bzi;
  int bo = z / nbi, bi = z - bo * nbi;
  int m0 = byi * BM, n0 = bxi * 128;

  if constexpr (MLEN) {
    if ((m0 & 511) >= mlens[m0 >> 9]) return;  // whole block beyond memory len (uniform)
  }

  const u16* Ab = A + bo * batAo + bi * batAi;
  const u16* Bb = Bt + bo * batBo + bi * batBi;
  long coff = bo * batCo + bi * batCi;
  const float* bias = nullptr;
  if constexpr (BIAS) bias = (bi == 0) ? bias0 : ((bi == 1) ? bias1 : bias2);

  __shared__ __align__(16) u16 As[3][BM * 32];
  __shared__ __align__(16) u16 Bs[3][128 * 32];

  int tid = threadIdx.x;
  int lane = tid & 63, wid = tid >> 6;
  int wm = wid >> 1, wn = wid & 1;
  int fr = lane & 15, grp = lane >> 4;

  f32x4 acc[BMW][4];
#pragma unroll
  for (int i = 0; i < BMW; i++)
#pragma unroll
    for (int j = 0; j < 4; j++) acc[i][j] = (f32x4){0.f, 0.f, 0.f, 0.f};

  const u16* ga = Ab + (long)(m0 + (tid >> 2)) * lda + ((tid & 3) << 3);
  const u16* gb = Bb + (long)(n0 + (tid >> 2)) * ldb + ((tid & 3) << 3);

  auto STAGE = [&](int buf, int kt) {
    u16* lA = &As[buf][tid * 8];
    u16* lB = &Bs[buf][tid * 8];
    gload16(ga + kt, lA);
    if constexpr (BM == 128) gload16(ga + kt + (long)64 * lda, lA + 2048);
    gload16(gb + kt, lB);
    gload16(gb + kt + (long)64 * ldb, lB + 2048);
  };

  auto COMPUTE = [&](int buf) {
    short8 av[BMW], bv[4];
#pragma unroll
    for (int i = 0; i < BMW; i++)
      av[i] = *(const short8*)&As[buf][(wm * BMW * 16 + i * 16 + fr) * 32 + grp * 8];
#pragma unroll
    for (int j = 0; j < 4; j++)
      bv[j] = *(const short8*)&Bs[buf][(wn * 64 + j * 16 + fr) * 32 + grp * 8];
#pragma unroll
    for (int i = 0; i < BMW; i++)
#pragma unroll
      for (int j = 0; j < 4; j++)
        acc[i][j] = __builtin_amdgcn_mfma_f32_16x16x32_bf16(av[i], bv[j], acc[i][j], 0, 0, 0);
  };

  int NT = K >> 5;                 // K/32 k-steps; all call sites have NT >= 16
  STAGE(0, 0);
  STAGE(1, 32);
  int cbuf = 0, sbuf = 2, kt = 64;
  for (int t = 0; t < NT - 2; ++t) {
    STAGE(sbuf, kt); kt += 32;     // tile t+2 into ring
    waitv<2 * LPS>();              // tile t's loads complete; t+1,t+2 stay in flight
    barrier_fenced();              // buf[t%3] ready for all waves
    COMPUTE(cbuf);
    lgk0_barrier();                // all waves done reading buf[t%3] (WAR for next STAGE)
    sbuf = cbuf; cbuf = (cbuf == 2) ? 0 : cbuf + 1;
  }
  waitv<LPS>();  barrier_fenced(); COMPUTE(cbuf); lgk0_barrier();
  cbuf = (cbuf == 2) ? 0 : cbuf + 1;
  waitv<0>();    barrier_fenced(); COMPUTE(cbuf);

  int rbase = m0 + wm * BMW * 16 + grp * 4;
  int cbase = n0 + wn * 64 + fr;
#pragma unroll
  for (int i = 0; i < BMW; i++) {
#pragma unroll
    for (int j = 0; j < 4; j++) {
      int col = cbase + j * 16;
      if (NCH && col >= N) continue;
      float bb = 0.0f;
      if constexpr (BIAS) bb = bias[col];
#pragma unroll
      for (int r2 = 0; r2 < 4; r2++) {
        int row = rbase + i * 16 + r2;
        float v = acc[i][j][r2] + bb;
        long idx = coff + (long)row * ldc + col;
        if constexpr (RES) v += R[idx];
        if constexpr (SWISH) v = v / (1.0f + expf(-v));
        if constexpr (OMODE == 0) ((u16*)Cv)[idx] = bfc(v);
        else ((float*)Cv)[idx] = v;
      }
    }
  }
}

// ---------------- fused flash attention ----------------
// Grid (b*H, qb). 256 thr = 4 waves; each wave owns WR=16*IQ q rows.
// Q/K/V all token-major [.,512] bf16 (col = h*64+d); V transposed into LDS at staging.
// O: [token][512]. CAUSAL requires IQ==2 (jmax*16 == kvmax*32 alignment).
template <int SKV, int KVBLK, bool CAUSAL, int IQ>
__global__ __launch_bounds__(256) void fattn_k(
    const u16* __restrict__ Q, const u16* __restrict__ Kg, const u16* __restrict__ Vg,
    u16* __restrict__ O, const int* __restrict__ lens) {
  constexpr int NJ  = KVBLK / 16;   // S col fragments per tile
  constexpr int NKV = KVBLK / 32;   // PV k-steps per tile
  constexpr int NT  = SKV / KVBLK;  // tiles
  constexpr int KST = 72;           // K lds row stride (u16), padded
  constexpr int VST = KVBLK + 8;    // Vt / P lds row stride (u16), padded
  constexpr int WR  = 16 * IQ;      // q rows per wave
  constexpr int WGR = 64 * IQ;      // q rows per workgroup
  constexpr int CH  = KVBLK / 32;   // 16B chunks per thread for K tile (= V tile)

  __shared__ __align__(16) u16 Ks[KVBLK * KST];
  __shared__ __align__(16) u16 Vs[64 * VST];
  __shared__ __align__(16) u16 Ps[WGR * VST];

  int bh = blockIdx.x; int b = bh >> 3, h = bh & 7;
  int row00 = blockIdx.y * WGR;
  int tid = threadIdx.x, lane = tid & 63, wid = tid >> 6;
  int fr = lane & 15, grp = lane >> 4;
  int len = lens[b];
  int row0w = row00 + wid * WR;

  // Q fragments: row = row0w + i*16 + fr, elems d = k2*32 + grp*8
  short8 qa[IQ][2];
  {
    const u16* qp = Q + ((long)b * Tc + row0w + fr) * 512 + h * 64 + grp * 8;
#pragma unroll
    for (int i = 0; i < IQ; i++)
#pragma unroll
      for (int k2 = 0; k2 < 2; k2++)
        qa[i][k2] = *(const short8*)(qp + (long)i * 16 * 512 + k2 * 32);
  }

  float m_run[IQ][4], l_run[IQ][4];
  f32x4 acc_o[IQ][4];
#pragma unroll
  for (int i = 0; i < IQ; i++)
#pragma unroll
    for (int r = 0; r < 4; r++) { m_run[i][r] = -1e30f; l_run[i][r] = 0.0f; }
#pragma unroll
  for (int i = 0; i < IQ; i++)
#pragma unroll
    for (int j = 0; j < 4; j++) acc_o[i][j] = (f32x4){0.f, 0.f, 0.f, 0.f};

  const u16* Kbase = Kg + ((long)b * SKV) * 512 + h * 64;
  const u16* Vbase = Vg + ((long)b * SKV) * 512 + h * 64;

  // tile count: causal bound (wg-uniform) and len bound (wg-uniform)
  int NTeff = NT;
  if constexpr (CAUSAL) NTeff = (row00 + WGR - 1) / KVBLK + 1;
  int lenT = (len + KVBLK - 1) / KVBLK;   // tiles wholly beyond len contribute 0
  if (lenT < NTeff) NTeff = lenT;

  short8 kreg[CH], vreg[CH];
  // preload tile 0 (K rows coalesced; V rows coalesced, transposed at LDS write)
#pragma unroll
  for (int c = 0; c < CH; c++) {
    int idx = tid + 256 * c; int kv = idx >> 3, s = idx & 7;
    kreg[c] = *(const short8*)(Kbase + (long)kv * 512 + s * 8);
    vreg[c] = *(const short8*)(Vbase + (long)kv * 512 + s * 8);
  }

  for (int t = 0; t < NTeff; t++) {
    int kv0 = t * KVBLK;
    __syncthreads();  // prior-tile LDS reads done (all waves)
#pragma unroll
    for (int c = 0; c < CH; c++) {
      int idx = tid + 256 * c; int kv = idx >> 3, s = idx & 7;
      *(short8*)&Ks[kv * KST + s * 8] = kreg[c];
#pragma unroll
      for (int j = 0; j < 8; j++)
        Vs[(s * 8 + j) * VST + kv] = (u16)vreg[c][j];   // transpose: Vs[d][kv]
    }
    __syncthreads();  // LDS ready
    // prefetch next tile into regs (overlaps with compute below)
    if (t + 1 < NTeff) {
      int kvn = kv0 + KVBLK;
#pragma unroll
      for (int c = 0; c < CH; c++) {
        int idx = tid + 256 * c; int kv = idx >> 3, s = idx & 7;
        kreg[c] = *(const short8*)(Kbase + (long)(kvn + kv) * 512 + s * 8);
        vreg[c] = *(const short8*)(Vbase + (long)(kvn + kv) * 512 + s * 8);
      }
    }

    int jmax = NJ;
    if constexpr (CAUSAL) {
      jmax = (row0w + WR - 1 - kv0) / 16 + 1;  // wave-uniform
      if (jmax > NJ) jmax = NJ;
    }

    // ---- S = Q @ K^T ----
    f32x4 accs[IQ][NJ];
    __builtin_amdgcn_s_setprio(1);
#pragma unroll
    for (int j = 0; j < NJ; j++) {
      if (CAUSAL && j >= jmax) continue;
      short8 bv0 = *(const short8*)&Ks[(j * 16 + fr) * KST + grp * 8];
      short8 bv1 = *(const short8*)&Ks[(j * 16 + fr) * KST + 32 + grp * 8];
#pragma unroll
      for (int i = 0; i < IQ; i++) {
        f32x4 a = __builtin_amdgcn_mfma_f32_16x16x32_bf16(qa[i][0], bv0, (f32x4){0.f,0.f,0.f,0.f}, 0, 0, 0);
        accs[i][j] = __builtin_amdgcn_mfma_f32_16x16x32_bf16(qa[i][1], bv1, a, 0, 0, 0);
      }
    }
    __builtin_amdgcn_s_setprio(0);

    // ---- online softmax ----
    float alpha[IQ][4];
#pragma unroll
    for (int i = 0; i < IQ; i++) {
#pragma unroll
      for (int r = 0; r < 4; r++) {
        int qrow = row0w + i * 16 + grp * 4 + r;
        float vmax = -1e30f;
#pragma unroll
        for (int j = 0; j < NJ; j++) {
          if (CAUSAL && j >= jmax) continue;
          int kvb = kv0 + j * 16 + fr;
          float s = accs[i][j][r] * 0.125f;
          bool msk = (kvb >= len) || (CAUSAL && kvb > qrow);
          s = msk ? -1e30f : s;
          accs[i][j][r] = s;
          vmax = fmaxf(vmax, s);
        }
        vmax = fmaxf(vmax, __shfl_xor(vmax, 1));
        vmax = fmaxf(vmax, __shfl_xor(vmax, 2));
        vmax = fmaxf(vmax, __shfl_xor(vmax, 4));
        vmax = fmaxf(vmax, __shfl_xor(vmax, 8));
        float mn = fmaxf(m_run[i][r], vmax);
        float al = __expf(m_run[i][r] - mn);
        m_run[i][r] = mn;
        alpha[i][r] = al;
        float rs = 0.0f;
#pragma unroll
        for (int j = 0; j < NJ; j++) {
          if (CAUSAL && j >= jmax) continue;
          float p = __expf(accs[i][j][r] - mn);
          accs[i][j][r] = p;
          rs += p;
        }
        rs += __shfl_xor(rs, 1);
        rs += __shfl_xor(rs, 2);
        rs += __shfl_xor(rs, 4);
        rs += __shfl_xor(rs, 8);
        l_run[i][r] = l_run[i][r] * al + rs;
      }
    }

    // ---- write P (bf16) to per-wave LDS region ----
#pragma unroll
    for (int i = 0; i < IQ; i++)
#pragma unroll
      for (int j = 0; j < NJ; j++) {
        if (CAUSAL && j >= jmax) continue;
#pragma unroll
        for (int r = 0; r < 4; r++) {
          int prow = wid * WR + i * 16 + grp * 4 + r;
          Ps[prow * VST + j * 16 + fr] = bfc(accs[i][j][r]);
        }
      }

    // ---- rescale O ----
#pragma unroll
    for (int i = 0; i < IQ; i++)
#pragma unroll
      for (int jd = 0; jd < 4; jd++)
#pragma unroll
        for (int r = 0; r < 4; r++)
          acc_o[i][jd][r] *= alpha[i][r];

    // ---- O += P @ V ----
    int kvmax = NKV;
    if constexpr (CAUSAL) {
      kvmax = (row0w + WR - 1 - kv0) / 32 + 1;  // == jmax*16/32 (IQ==2)
      if (kvmax > NKV) kvmax = NKV;
    }
    __builtin_amdgcn_s_setprio(1);
#pragma unroll
    for (int kk = 0; kk < NKV; kk++) {
      if (CAUSAL && kk >= kvmax) continue;
      short8 pa[IQ];
#pragma unroll
      for (int i = 0; i < IQ; i++)
        pa[i] = *(const short8*)&Ps[(wid * WR + i * 16 + fr) * VST + kk * 32 + grp * 8];
#pragma unroll
      for (int jd = 0; jd < 4; jd++) {
        short8 vb = *(const short8*)&Vs[(jd * 16 + fr) * VST + kk * 32 + grp * 8];
#pragma unroll
        for (int i = 0; i < IQ; i++)
          acc_o[i][jd] = __builtin_amdgcn_mfma_f32_16x16x32_bf16(pa[i], vb, acc_o[i][jd], 0, 0, 0);
      }
    }
    __builtin_amdgcn_s_setprio(0);
  }

  // ---- finalize: O / l ----
#pragma unroll
  for (int i = 0; i < IQ; i++) {
#pragma unroll
    for (int r = 0; r < 4; r++) {
      float inv = 1.0f / l_run[i][r];
      long tok = (long)b * Tc + row0w + i * 16 + grp * 4 + r;
#pragma unroll
      for (int jd = 0; jd < 4; jd++)
        O[tok * 512 + h * 64 + jd * 16 + fr] = bfc(acc_o[i][jd][r] * inv);
    }
  }
}

// ---------------- host launcher ----------------
extern "C" void kernel_launch(void* const* d_in, const int* in_sizes, int n_in,
                              void* d_out, int out_size, void* d_ws, size_t ws_size,
                              hipStream_t stream) {
  const float* memory   = (const float*)d_in[0];
  const int*   mem_lens = (const int*)d_in[1];
  const int*   ys       = (const int*)d_in[2];
  const int*   ys_lens  = (const int*)d_in[3];
  const float* emb      = (const float*)d_in[4];
  const float* w_out    = (const float*)d_in[5];
  const float* b_out    = (const float*)d_in[6];
  const float* pp[26];
  for (int i = 0; i < 26; i++) pp[i] = (const float*)d_in[7 + i];

  // ---- ws layout (~126.4 MB of the 256 MiB ws) ----
  constexpr long PLW = 4194304;  // bf16 elems of transposed weights per layer
  constexpr long OFF_SAQ = 0, OFF_SAK = 262144, OFF_SAV = 524288, OFF_SAO = 786432,
                 OFF_CAQ = 1048576, OFF_CAK = 1310720, OFF_CAV = 1572864,
                 OFF_CAO = 1835008, OFF_FF1 = 2097152, OFF_FF2 = 3145728,
                 OFF_WOUT = 6 * PLW;
  u16*   Wt   = (u16*)d_ws;                          // 25,427,968 u16
  float* X    = (float*)(Wt + 25427968);             // 2,097,152 f32
  u16*   TO   = (u16*)(X + 2097152);                 // 2,097,152 bf16
  u16*   QKV  = TO + 2097152;                        // 3 x 2,097,152 bf16
  u16*   memb = QKV + 3 * 2097152;                   // 8,388,608 bf16
  u16*   Kb   = memb + 8388608;                      // 8,388,608 bf16 (cross K)
  u16*   SCR  = Kb + 8388608;                        // 8,388,608 bf16 (CA V / FF hidden)
  float* OUT  = (float*)d_out;

  // 8 square (512x512) weight families in one dispatch (z = widx*6 + l)
  PtrPack8 P8;
  P8.p[0] = pp[2];  P8.p[1] = pp[4];  P8.p[2] = pp[6];  P8.p[3] = pp[8];
  P8.p[4] = pp[12]; P8.p[5] = pp[14]; P8.p[6] = pp[16]; P8.p[7] = pp[18];
  wtrans8_k<<<dim3(16, 16, 48), 256, 0, stream>>>(P8, Wt, PLW);
  wtrans_k<<<dim3(64, 16, Lc), 256, 0, stream>>>(pp[22], Wt + OFF_FF1, 512, 2048, 1048576, PLW);
  wtrans_k<<<dim3(16, 64, Lc), 256, 0, stream>>>(pp[24], Wt + OFF_FF2, 2048, 512, 1048576, PLW);
  wtrans_k<<<dim3(16, 16, 1), 256, 0, stream>>>(w_out, Wt + OFF_WOUT, 512, 500, 0, 0);

  f2b_k<<<(NMEM * Dc / 4 + 255) / 256, 256, 0, stream>>>(memory, memb, (long)NMEM * Dc);
  embed_pe_k<<<NTOK, 256, 0, stream>>>(ys, emb, X);

  for (int l = 0; l < Lc; l++) {
    const u16* WtL = Wt + (long)l * PLW;

    // ======== self-attention ========
    layernorm_k<<<NTOK, 256, 0, stream>>>(X, pp[0] + (long)l * Dc, pp[1] + (long)l * Dc, TO);
    mgemm_k<4, 0, true, false, false, false, false><<<dim3(4, 32, 3), 256, 0, stream>>>(
        TO, WtL + OFF_SAQ, pp[3] + (long)l * Ac, pp[5] + (long)l * Ac, pp[7] + (long)l * Ac,
        QKV, nullptr, nullptr, 512, 512, 512, 512, 512, 3, 0, 0, 0, 262144, 0, 2097152);
    fattn_k<128, 128, true, 2><<<dim3(256, 1), 256, 0, stream>>>(
        QKV, QKV + 2097152, QKV + 2 * 2097152, TO, ys_lens);
    mgemm_k<2, 1, true, true, false, false, false><<<dim3(4, 64, 1), 256, 0, stream>>>(
        TO, WtL + OFF_SAO, pp[9] + (long)l * Dc, nullptr, nullptr, X, X, nullptr,
        512, 512, 512, 512, 512, 1, 0, 0, 0, 0, 0, 0);

    // ======== cross-attention ========
    layernorm_k<<<NTOK, 256, 0, stream>>>(X, pp[10] + (long)l * Dc, pp[11] + (long)l * Dc, TO);
    mgemm_k<2, 0, true, false, false, false, false><<<dim3(4, 64, 1), 256, 0, stream>>>(
        TO, WtL + OFF_CAQ, pp[13] + (long)l * Ac, nullptr, nullptr, QKV, nullptr, nullptr,
        512, 512, 512, 512, 512, 1, 0, 0, 0, 0, 0, 0);
    // K -> Kb (bi=0), V -> SCR (bi=1); blocks fully beyond mem_lens skipped (MLEN)
    mgemm_k<4, 0, true, false, false, false, true><<<dim3(4, 128, 2), 256, 0, stream>>>(
        memb, WtL + OFF_CAK, pp[15] + (long)l * Ac, pp[17] + (long)l * Ac, nullptr,
        Kb, nullptr, mem_lens, 512, 512, 512, 512, 512, 2, 0, 0, 0, 262144, 0, 8388608);
    fattn_k<512, 128, false, 1><<<dim3(256, 2), 256, 0, stream>>>(
        QKV, Kb, SCR, TO, mem_lens);
    mgemm_k<2, 1, true, true, false, false, false><<<dim3(4, 64, 1), 256, 0, stream>>>(
        TO, WtL + OFF_CAO, pp[19] + (long)l * Dc, nullptr, nullptr, X, X, nullptr,
        512, 512, 512, 512, 512, 1, 0, 0, 0, 0, 0, 0);

    // ======== feed-forward ========
    layernorm_k<<<NTOK, 256, 0, stream>>>(X, pp[20] + (long)l * Dc, pp[21] + (long)l * Dc, TO);
    mgemm_k<4, 0, true, false, true, false, false><<<dim3(16, 32, 1), 256, 0, stream>>>(
        TO, WtL + OFF_FF1, pp[23] + (long)l * FFc, nullptr, nullptr, SCR, nullptr, nullptr,
        2048, 512, 512, 512, 2048, 1, 0, 0, 0, 0, 0, 0);
    mgemm_k<2, 1, true, true, false, false, false><<<dim3(4, 64, 1), 256, 0, stream>>>(
        SCR, WtL + OFF_FF2, pp[25] + (long)l * Dc, nullptr, nullptr, X, X, nullptr,
        512, 2048, 2048, 2048, 512, 1, 0, 0, 0, 0, 0, 0);
  }

  // final projection: X -> bf16 -> logits fp32 (N=500, ldc=500)
  f2b_k<<<(NTOK * Dc / 4 + 255) / 256, 256, 0, stream>>>(X, TO, (long)NTOK * Dc);
  mgemm_k<2, 1, true, false, false, true, false><<<dim3(4, 64, 1), 256, 0, stream>>>(
      TO, Wt + OFF_WOUT, b_out, nullptr, nullptr, OUT, nullptr, nullptr,
      500, 512, 512, 512, 500, 1, 0, 0, 0, 0, 0, 0);
}